// Round 11
// baseline (825.334 us; speedup 1.0000x reference)
//
#include <hip/hip_runtime.h>
#include <hip/hip_bf16.h>

#define BATCH 32
#define NN 511
#define FEAT 512
#define NFEAT ((long)32*NN*FEAT)   // 8372224

typedef _Float16 half8 __attribute__((ext_vector_type(8)));
typedef float f32x4 __attribute__((ext_vector_type(4)));

__device__ __forceinline__ float bf2f(unsigned short u){
  union { unsigned int i; float f; } v; v.i = ((unsigned int)u) << 16; return v.f;
}
__device__ __forceinline__ float sigm(float x){ return 1.0f/(1.0f+expf(-x)); }
__device__ __forceinline__ float ldf(const void* p, long i, int f32){
  return f32 ? ((const float*)p)[i] : bf2f(((const unsigned short*)p)[i]);
}
__device__ __forceinline__ void gload_lds16(const _Float16* g, _Float16* l){
  __builtin_amdgcn_global_load_lds(
      (const __attribute__((address_space(1))) unsigned int*)g,
      (__attribute__((address_space(3))) unsigned int*)l, 16, 0, 0);
}

// ---------------- dtype probe: 0 = bf16, 1 = fp32 ----------------
__global__ void detect_kernel(const unsigned short* __restrict__ p, int* __restrict__ flag){
  __shared__ int cnt;
  if (threadIdx.x == 0) cnt = 0;
  __syncthreads();
  int local = 0;
  for (int i = threadIdx.x; i < 4096; i += 256){
    unsigned short u = p[2*i];
    int e = (u >> 7) & 0xFF;
    if (u != 0 && e >= 117 && e <= 133) local++;
  }
  atomicAdd(&cnt, local);
  __syncthreads();
  if (threadIdx.x == 0) *flag = (cnt > 2048) ? 0 : 1;
}

// ---------------- single fused conversion kernel ----------------
__global__ void cvt_all(
    const void* __restrict__ feat, const void* __restrict__ Wiou,
    const void* __restrict__ Wfeiou, const void* __restrict__ Wf,
    const void* __restrict__ Wfef, const void* __restrict__ eh,
    const void* __restrict__ Wln, const void* __restrict__ Wlf,
    const void* __restrict__ biou, const void* __restrict__ bfv,
    _Float16* __restrict__ feat_h, _Float16* __restrict__ Wiou_h,
    _Float16* __restrict__ Wfeiou_h, _Float16* __restrict__ Wf_h,
    _Float16* __restrict__ Wfef_h, _Float16* __restrict__ eh_h,
    _Float16* __restrict__ Wln_h, _Float16* __restrict__ Wlf_h,
    float* __restrict__ biou_f, float* __restrict__ bf_f,
    const int* __restrict__ flag)
{
  long g = ((long)blockIdx.x*256 + threadIdx.x)*8;
  int f32 = *flag;
  const long S1 = NFEAT;            // feat
  const long S2 = S1 + 786432;      // Wiou
  const long S3 = S2 + 786432;      // Wfeiou
  const long S4 = S3 + 262144;      // Wf
  const long S5 = S4 + 262144;      // Wfef
  const long S6 = S5 + 32768;       // eh
  const long S7 = S6 + 524288;      // Wln
  const long S8 = S7 + 524288;      // Wlf  (= 11550720)
  const long S9 = S8 + 1536;        // bias iou (fp32 out)
  const long SA = S9 + 512;         // bias f
  if (g >= SA) return;
  if (g >= S9){
    long o = g - S9;
    for (int q = 0; q < 8; q++) bf_f[o+q] = ldf(bfv, o+q, f32);
    return;
  }
  if (g >= S8){
    long o = g - S8;
    for (int q = 0; q < 8; q++) biou_f[o+q] = ldf(biou, o+q, f32);
    return;
  }
  const void* src; _Float16* dst; long off;
  if      (g < S1){ src=feat;   dst=feat_h;   off=g; }
  else if (g < S2){ src=Wiou;   dst=Wiou_h;   off=g-S1; }
  else if (g < S3){ src=Wfeiou; dst=Wfeiou_h; off=g-S2; }
  else if (g < S4){ src=Wf;     dst=Wf_h;     off=g-S3; }
  else if (g < S5){ src=Wfef;   dst=Wfef_h;   off=g-S4; }
  else if (g < S6){ src=eh;     dst=eh_h;     off=g-S5; }
  else if (g < S7){ src=Wln;    dst=Wln_h;    off=g-S6; }
  else            { src=Wlf;    dst=Wlf_h;    off=g-S7; }
  #pragma unroll
  for (int q = 0; q < 8; q++) dst[off+q] = (_Float16)ldf(src, off+q, f32);
}

// ---------------- e_node/e_forw via MFMA ----------------
__global__ __launch_bounds__(64) void e_mfma(
    const _Float16* __restrict__ eh,
    const _Float16* __restrict__ Wn,
    const _Float16* __restrict__ Wf,
    float* __restrict__ e_node, float* __restrict__ e_forw)
{
  int lane = threadIdx.x;
  int m = lane & 15, quad = lane >> 4;
  int n = blockIdx.x*16 + m;
  const _Float16* wrow = (n < 512) ? (Wn + (long)n*1024) : (Wf + (long)(n-512)*1024);
  f32x4 acc[2] = {};
  for (int ks = 0; ks < 32; ks++){
    int kk = ks*32 + quad*8;
    half8 bfr = *(const half8*)(wrow + kk);
    #pragma unroll
    for (int i = 0; i < 2; i++){
      half8 afr = *(const half8*)(eh + (long)(i*16 + m)*1024 + kk);
      acc[i] = __builtin_amdgcn_mfma_f32_16x16x32_f16(afr, bfr, acc[i], 0, 0, 0);
    }
  }
  float* dst = (n < 512) ? e_node : e_forw;
  int col = (n < 512) ? n : (n - 512);
  #pragma unroll
  for (int i = 0; i < 2; i++)
    #pragma unroll
    for (int reg = 0; reg < 4; reg++){
      int b = i*16 + quad*4 + reg;
      dst[b*FEAT + col] = acc[i][reg];
    }
}

// ---------------- feat2: one wave per (node,batch); fully vectorized ---------------
__global__ __launch_bounds__(64) void feat2_kernel(
    const _Float16* __restrict__ feat,
    const int* __restrict__ finlist,
    const float* __restrict__ e_node,
    _Float16* __restrict__ feat2){
  int i = blockIdx.x, b = blockIdx.y, lane = threadIdx.x;
  int s0 = finlist[(b*NN+i)*2+0];
  int e0 = finlist[(b*NN+i)*2+1];
  s0 = min(max(s0, 0), NN-1);
  e0 = min(max(e0, s0), NN-1);
  int w = min(e0 - s0 + 1, 4);

  const _Float16* base = feat + ((long)b*NN + s0)*FEAT + lane*8;
  half8 v[4];
  #pragma unroll
  for (int q = 0; q < 4; q++){
    if (q < w) v[q] = *(const half8*)(base + (long)q*FEAT);
    else       v[q] = half8{};
  }
  const float* ep = e_node + b*FEAT + lane*8;
  f32x4 ev0 = *(const f32x4*)ep;
  f32x4 ev1 = *(const f32x4*)(ep+4);
  float en[8] = {ev0[0],ev0[1],ev0[2],ev0[3],ev1[0],ev1[1],ev1[2],ev1[3]};

  float s[4];
  #pragma unroll
  for (int q = 0; q < 4; q++){
    float acc = 0.f;
    #pragma unroll
    for (int j = 0; j < 8; j++) acc += (float)v[q][j]*en[j];
    s[q] = acc;
  }
  #pragma unroll
  for (int q = 0; q < 4; q++)
    #pragma unroll
    for (int off = 1; off < 64; off <<= 1)
      s[q] += __shfl_xor(s[q], off, 64);

  float mx = -1e30f;
  #pragma unroll
  for (int q = 0; q < 4; q++){
    if (q >= w) s[q] = -1e30f;
    mx = fmaxf(mx, s[q]);
  }
  float p[4]; float den = 0.f;
  #pragma unroll
  for (int q = 0; q < 4; q++){ p[q] = (q < w) ? expf(s[q]-mx) : 0.f; den += p[q]; }
  float inv = 1.f/den;

  half8 o;
  #pragma unroll
  for (int j = 0; j < 8; j++){
    float acc = 0.f;
    #pragma unroll
    for (int q = 0; q < 4; q++) acc += p[q]*(float)v[q][j];
    o[j] = (_Float16)(acc*inv);
  }
  *(half8*)(feat2 + ((long)b*NN + i)*FEAT + lane*8) = o;
}

// ---------------- fe GEMM: LDS-staged, double-buffered (verified R9/R10) ----------
__global__ __launch_bounds__(256) void fe_gemm(
    const _Float16* __restrict__ feat2,
    const _Float16* __restrict__ Wfeiou, const _Float16* __restrict__ Wfef,
    const float* __restrict__ biou, const float* __restrict__ bf,
    _Float16* __restrict__ fe_iou, _Float16* __restrict__ fe_f)
{
  __shared__ _Float16 Abuf[2][128*64];
  __shared__ _Float16 Bbuf[2][64*64];
  const int MT = 32*NN;                // 16352
  int tid = threadIdx.x;
  int wv = tid >> 6, lane = tid & 63;
  int m = lane & 15, quad = lane >> 4;
  int cg = blockIdx.y;
  int rowbase = blockIdx.x*128;
  int which = (cg < 24) ? 0 : 1;
  int colbase = which ? (cg-24)*64 : cg*64;
  const _Float16* W = which ? Wfef : Wfeiou;

  const _Float16* gA[4];
  {
    #pragma unroll
    for (int t = 0; t < 4; t++){
      int c = wv*64 + lane + t*256;
      int rt = c >> 3, kc = c & 7;
      int r = rowbase + rt; if (r >= MT) r = MT - 1;
      int bb = r / NN, node = r - bb*NN;
      int srcn = which ? ((node >= 1) ? ((node-1)>>1) : 0) : node;
      gA[t] = feat2 + ((long)bb*NN + srcn)*FEAT + ((kc ^ (rt & 7))<<3);
    }
  }
  const _Float16* gB[2];
  {
    #pragma unroll
    for (int t = 0; t < 2; t++){
      int c = wv*64 + lane + t*256;
      int rt = c >> 3, kc = c & 7;
      gB[t] = W + (long)(colbase + rt)*FEAT + ((kc ^ (rt & 7))<<3);
    }
  }

  int aoff[2][2], boff[4][2];
  #pragma unroll
  for (int i = 0; i < 2; i++)
    #pragma unroll
    for (int ks = 0; ks < 2; ks++){
      int rt = wv*32 + i*16 + m;
      aoff[i][ks] = rt*128 + (((ks*4 + quad) ^ (rt & 7))<<4);
    }
  #pragma unroll
  for (int j = 0; j < 4; j++)
    #pragma unroll
    for (int ks = 0; ks < 2; ks++){
      int rt = j*16 + m;
      boff[j][ks] = rt*128 + (((ks*4 + quad) ^ (rt & 7))<<4);
    }

  f32x4 acc[2][4] = {};

  #pragma unroll
  for (int t = 0; t < 4; t++)
    gload_lds16(gA[t], &Abuf[0][(wv*64 + t*256)*8]);
  #pragma unroll
  for (int t = 0; t < 2; t++)
    gload_lds16(gB[t], &Bbuf[0][(wv*64 + t*256)*8]);

  for (int it = 0; it < 8; ++it){
    int cur = it & 1;
    __syncthreads();
    if (it < 7){
      int kk = (it+1)*64;
      #pragma unroll
      for (int t = 0; t < 4; t++)
        gload_lds16(gA[t] + kk, &Abuf[cur^1][(wv*64 + t*256)*8]);
      #pragma unroll
      for (int t = 0; t < 2; t++)
        gload_lds16(gB[t] + kk, &Bbuf[cur^1][(wv*64 + t*256)*8]);
    }
    const char* Ab_ = (const char*)&Abuf[cur][0];
    const char* Bb_ = (const char*)&Bbuf[cur][0];
    #pragma unroll
    for (int ks = 0; ks < 2; ks++){
      half8 a0 = *(const half8*)(Ab_ + aoff[0][ks]);
      half8 a1 = *(const half8*)(Ab_ + aoff[1][ks]);
      #pragma unroll
      for (int j = 0; j < 4; j++){
        half8 bfr = *(const half8*)(Bb_ + boff[j][ks]);
        acc[0][j] = __builtin_amdgcn_mfma_f32_16x16x32_f16(a0, bfr, acc[0][j], 0, 0, 0);
        acc[1][j] = __builtin_amdgcn_mfma_f32_16x16x32_f16(a1, bfr, acc[1][j], 0, 0, 0);
      }
    }
  }
  __syncthreads();

  const float* bias = which ? bf : biou;
  float bs[4];
  #pragma unroll
  for (int j = 0; j < 4; j++) bs[j] = bias[colbase + j*16 + m];

  _Float16* sl = &Abuf[0][wv*16*72];
  int lr = lane >> 2;
  int lc = (lane & 3) * 16;
  #pragma unroll
  for (int i = 0; i < 2; i++){
    #pragma unroll
    for (int j = 0; j < 4; j++)
      #pragma unroll
      for (int reg = 0; reg < 4; reg++)
        sl[(quad*4+reg)*72 + j*16 + m] = (_Float16)(acc[i][j][reg] + bs[j]);
    half8 o0 = *(const half8*)&sl[lr*72 + lc];
    half8 o1 = *(const half8*)&sl[lr*72 + lc + 8];
    int r = rowbase + wv*32 + i*16 + lr;
    if (r < MT){
      int b = r / NN, node = r - b*NN;
      if (which == 0){
        _Float16* dst = fe_iou + ((long)b*NN + node)*1536 + colbase + lc;
        *(half8*)dst = o0; *(half8*)(dst+8) = o1;
      } else if (node >= 1){
        _Float16* dst = fe_f + ((long)b*NN + node)*FEAT + colbase + lc;
        *(half8*)dst = o0; *(half8*)(dst+8) = o1;
      }
    }
  }
}

// ---------------- staged per-level GEMM (P>=32, verified R10) ---------
__global__ __launch_bounds__(256) void gemm_level_staged(
    int P, int lp,
    const _Float16* __restrict__ hbuf, const _Float16* __restrict__ hsum,
    const _Float16* __restrict__ Wiou, const _Float16* __restrict__ Wf,
    _Float16* __restrict__ fe_iou, _Float16* __restrict__ fe_f)
{
  __shared__ _Float16 Abuf[2][128*64];
  __shared__ _Float16 Bbuf[2][64*64];
  int Mtot = P << 5;
  int tid = threadIdx.x;
  int wv = tid >> 6, lane = tid & 63;
  int m = lane & 15, quad = lane >> 4;
  int cg = blockIdx.y;
  int rowbase = blockIdx.x*128;
  int p0 = P - 1, c0 = 2*P - 1;
  int which, colbase;
  if (cg < 24)      { which = 0; colbase = cg*64; }
  else if (cg < 32) { which = 1; colbase = (cg-24)*64; }
  else              { which = 2; colbase = (cg-32)*64; }
  const _Float16* W = (which == 0) ? Wiou : Wf;

  const _Float16* gA[4];
  {
    #pragma unroll
    for (int t = 0; t < 4; t++){
      int c = wv*64 + lane + t*256;
      int rt = c >> 3, kc = c & 7;
      int r = rowbase + rt; if (r >= Mtot) r = Mtot - 1;
      int bb = r >> lp, p = r & (P-1);
      const _Float16* base;
      if (which == 0) base = hsum + ((long)bb*128 + p)*FEAT;
      else            base = hbuf + ((long)bb*NN + c0 + 2*p + (which==2))*FEAT;
      gA[t] = base + ((kc ^ (rt & 7))<<3);
    }
  }
  const _Float16* gB[2];
  {
    #pragma unroll
    for (int t = 0; t < 2; t++){
      int c = wv*64 + lane + t*256;
      int rt = c >> 3, kc = c & 7;
      gB[t] = W + (long)(colbase + rt)*FEAT + ((kc ^ (rt & 7))<<3);
    }
  }

  int aoff[2][2], boff[4][2];
  #pragma unroll
  for (int i = 0; i < 2; i++)
    #pragma unroll
    for (int ks = 0; ks < 2; ks++){
      int rt = wv*32 + i*16 + m;
      aoff[i][ks] = rt*128 + (((ks*4 + quad) ^ (rt & 7))<<4);
    }
  #pragma unroll
  for (int j = 0; j < 4; j++)
    #pragma unroll
    for (int ks = 0; ks < 2; ks++){
      int rt = j*16 + m;
      boff[j][ks] = rt*128 + (((ks*4 + quad) ^ (rt & 7))<<4);
    }

  f32x4 acc[2][4] = {};

  #pragma unroll
  for (int t = 0; t < 4; t++)
    gload_lds16(gA[t], &Abuf[0][(wv*64 + t*256)*8]);
  #pragma unroll
  for (int t = 0; t < 2; t++)
    gload_lds16(gB[t], &Bbuf[0][(wv*64 + t*256)*8]);

  for (int it = 0; it < 8; ++it){
    int cur = it & 1;
    __syncthreads();
    if (it < 7){
      int kk = (it+1)*64;
      #pragma unroll
      for (int t = 0; t < 4; t++)
        gload_lds16(gA[t] + kk, &Abuf[cur^1][(wv*64 + t*256)*8]);
      #pragma unroll
      for (int t = 0; t < 2; t++)
        gload_lds16(gB[t] + kk, &Bbuf[cur^1][(wv*64 + t*256)*8]);
    }
    const char* Ab_ = (const char*)&Abuf[cur][0];
    const char* Bb_ = (const char*)&Bbuf[cur][0];
    #pragma unroll
    for (int ks = 0; ks < 2; ks++){
      half8 a0 = *(const half8*)(Ab_ + aoff[0][ks]);
      half8 a1 = *(const half8*)(Ab_ + aoff[1][ks]);
      #pragma unroll
      for (int j = 0; j < 4; j++){
        half8 bfr = *(const half8*)(Bb_ + boff[j][ks]);
        acc[0][j] = __builtin_amdgcn_mfma_f32_16x16x32_f16(a0, bfr, acc[0][j], 0, 0, 0);
        acc[1][j] = __builtin_amdgcn_mfma_f32_16x16x32_f16(a1, bfr, acc[1][j], 0, 0, 0);
      }
    }
  }
  __syncthreads();

  float* fsl = (float*)((char*)&Abuf[0][0] + wv*(16*68*4));
  int lr = lane >> 2;
  int lc = (lane & 3) * 16;
  #pragma unroll
  for (int i = 0; i < 2; i++){
    #pragma unroll
    for (int j = 0; j < 4; j++)
      #pragma unroll
      for (int reg = 0; reg < 4; reg++)
        fsl[(quad*4+reg)*68 + j*16 + m] = acc[i][j][reg];
    f32x4 a0 = *(const f32x4*)&fsl[lr*68 + lc];
    f32x4 a1 = *(const f32x4*)&fsl[lr*68 + lc + 4];
    f32x4 a2 = *(const f32x4*)&fsl[lr*68 + lc + 8];
    f32x4 a3 = *(const f32x4*)&fsl[lr*68 + lc + 12];
    int r = rowbase + wv*32 + i*16 + lr;
    if (r < Mtot){
      int b = r >> lp, p = r & (P-1);
      _Float16* dst;
      if (which == 0) dst = fe_iou + ((long)b*NN + p0 + p)*1536 + colbase + lc;
      else            dst = fe_f  + ((long)b*NN + c0 + 2*p + (which-1))*FEAT + colbase + lc;
      half8 f0 = *(const half8*)dst;
      half8 f1 = *(const half8*)(dst+8);
      half8 o0, o1;
      #pragma unroll
      for (int q = 0; q < 4; q++){
        o0[q]   = (_Float16)(a0[q] + (float)f0[q]);
        o0[q+4] = (_Float16)(a1[q] + (float)f0[q+4]);
        o1[q]   = (_Float16)(a2[q] + (float)f1[q]);
        o1[q+4] = (_Float16)(a3[q] + (float)f1[q+4]);
      }
      *(half8*)dst = o0; *(half8*)(dst+8) = o1;
    }
  }
}

// ---------------- fused tail: levels P=16,8,4,2,1; one block per batch ----------
// Phase A: 40 col-tiles (24 iou from hsum + 8 fl + 8 fr from h) of 16x64 MFMA
//          GEMM over 16 waves; scalar single-rounded RMW into fe_iou/fe_f.
// Phase B: paired pointwise (same math as pw_level) + hsum for next level.
// Intra-block global producer-consumer: __threadfence_block + __syncthreads.
__global__ __launch_bounds__(1024) void tail_levels(
    const _Float16* __restrict__ Wiou, const _Float16* __restrict__ Wf,
    _Float16* __restrict__ fe_iou, _Float16* __restrict__ fe_f,
    float* __restrict__ c, _Float16* __restrict__ h,
    _Float16* __restrict__ hsum)
{
  int b = blockIdx.x;
  int tid = threadIdx.x;
  int wv = tid >> 6, lane = tid & 63;
  int m = lane & 15, quad = lane >> 4;

  for (int P = 16; P >= 1; P >>= 1){
    int p0 = P - 1, c0 = 2*P - 1;
    // ---- phase A: GEMM ----
    for (int t = wv; t < 40; t += 16){
      int which, colbase;
      if (t < 24)      { which = 0; colbase = t*64; }
      else if (t < 32) { which = 1; colbase = (t-24)*64; }
      else             { which = 2; colbase = (t-32)*64; }
      const _Float16* W = (which == 0) ? Wiou : Wf;
      int pm = (m < P) ? m : (P-1);
      const _Float16* arow;
      if (which == 0) arow = hsum + ((long)b*128 + pm)*FEAT;
      else            arow = h + ((long)b*NN + c0 + 2*pm + ((which==2)?1:0))*FEAT;
      f32x4 acc[4] = {};
      for (int ks = 0; ks < 16; ks++){
        half8 av = *(const half8*)(arow + ks*32 + quad*8);
        #pragma unroll
        for (int j = 0; j < 4; j++){
          half8 bv = *(const half8*)(W + (long)(colbase + j*16 + m)*FEAT + ks*32 + quad*8);
          acc[j] = __builtin_amdgcn_mfma_f32_16x16x32_f16(av, bv, acc[j], 0, 0, 0);
        }
      }
      #pragma unroll
      for (int j = 0; j < 4; j++)
        #pragma unroll
        for (int reg = 0; reg < 4; reg++){
          int pr = quad*4 + reg;
          if (pr < P){
            int n = colbase + j*16 + m;
            _Float16* dst;
            if (which == 0) dst = fe_iou + ((long)b*NN + p0 + pr)*1536 + n;
            else            dst = fe_f  + ((long)b*NN + c0 + 2*pr + (which-1))*FEAT + n;
            *dst = (_Float16)(acc[j][reg] + (float)*dst);
          }
        }
    }
    __threadfence_block();
    __syncthreads();
    // ---- phase B: pointwise ----
    if (P > 1){
      int base = tid*8;
      int r2 = base >> 9, f0 = base & 511;
      if (r2 < (P>>1)){
        const _Float16* row0 = fe_iou + ((long)b*NN + p0 + 2*r2)*1536;
        const _Float16* row1 = row0 + 1536;
        const _Float16* fl0 = fe_f + ((long)b*NN + c0 + 4*r2)*FEAT;
        long cl0 = ((long)b*NN + c0 + 4*r2)*FEAT;
        long po0 = ((long)b*NN + p0 + 2*r2)*FEAT;
        long so = ((long)b*128 + r2)*FEAT;
        #pragma unroll
        for (int q = 0; q < 8; q++){
          int f = f0 + q;
          float cs0 = sigm((float)fl0[f])*c[cl0+f] + sigm((float)fl0[FEAT+f])*c[cl0+FEAT+f];
          float cn0 = sigm((float)row0[f])*fmaxf((float)row0[2*FEAT+f], 0.f) + cs0;
          _Float16 hn0 = (_Float16)(sigm((float)row0[FEAT+f])*tanhf(cn0));
          const _Float16* fl1 = fl0 + 2*FEAT;
          long cl1 = cl0 + 2*FEAT;
          float cs1 = sigm((float)fl1[f])*c[cl1+f] + sigm((float)fl1[FEAT+f])*c[cl1+FEAT+f];
          float cn1 = sigm((float)row1[f])*fmaxf((float)row1[2*FEAT+f], 0.f) + cs1;
          _Float16 hn1 = (_Float16)(sigm((float)row1[FEAT+f])*tanhf(cn1));
          c[po0+f] = cn0; h[po0+f] = hn0;
          c[po0+FEAT+f] = cn1; h[po0+FEAT+f] = hn1;
          hsum[so+f] = hn0 + hn1;
        }
      }
    } else {
      int base = tid*8;
      if (base < 512){
        const _Float16* row = fe_iou + ((long)b*NN)*1536;
        const _Float16* fl = fe_f + ((long)b*NN + 1)*FEAT;
        long cl = ((long)b*NN + 1)*FEAT;
        long po = ((long)b*NN)*FEAT;
        #pragma unroll
        for (int q = 0; q < 8; q++){
          int f = base + q;
          float cs = sigm((float)fl[f])*c[cl+f] + sigm((float)fl[FEAT+f])*c[cl+FEAT+f];
          float cn = sigm((float)row[f])*fmaxf((float)row[2*FEAT+f], 0.f) + cs;
          float hn = sigm((float)row[FEAT+f])*tanhf(cn);
          c[po+f] = cn; h[po+f] = (_Float16)hn;
        }
      }
    }
    __threadfence_block();
    __syncthreads();
  }
}

// ---------------- level-0 pointwise (leaves), paired, + hsum (verified R10) ------
__global__ void pw_leaf(const _Float16* __restrict__ fe_iou, float* __restrict__ c,
                        _Float16* __restrict__ h, _Float16* __restrict__ hsum){
  int r2 = blockIdx.x, b = blockIdx.y, t = threadIdx.x;   // r2 < 128
  int l0 = 255 + 2*r2;
  const _Float16* row0 = fe_iou + ((long)b*NN + l0)*1536;
  const _Float16* row1 = row0 + 1536;
  long off0 = ((long)b*NN + l0)*FEAT;
  long off1 = off0 + FEAT;
  long so = ((long)b*128 + r2)*FEAT;
  #pragma unroll
  for (int e = 0; e < 2; e++){
    int f = t + e*256;
    float cn0 = sigm((float)row0[f])*fmaxf((float)row0[2*FEAT+f], 0.f);
    _Float16 hn0 = (_Float16)(sigm((float)row0[FEAT+f])*tanhf(cn0));
    float cn1 = sigm((float)row1[f])*fmaxf((float)row1[2*FEAT+f], 0.f);
    _Float16 hn1 = (_Float16)(sigm((float)row1[FEAT+f])*tanhf(cn1));
    c[off0+f] = cn0; h[off0+f] = hn0;
    c[off1+f] = cn1; h[off1+f] = hn1;
    hsum[so+f] = hn0 + hn1;
  }
}

// ---------------- level-n pointwise, paired, + hsum (verified R10) ----------------
__global__ void pw_level(const _Float16* __restrict__ fe_iou, const _Float16* __restrict__ fe_f,
                         float* __restrict__ c, _Float16* __restrict__ h,
                         _Float16* __restrict__ hsum,
                         int P, int p0, int c0){
  int r2 = blockIdx.x, b = blockIdx.y, t = threadIdx.x;
  int pr0 = 2*r2, pr1 = 2*r2 + 1;
  bool has1 = (pr1 < P);
  const _Float16* row0 = fe_iou + ((long)b*NN + p0 + pr0)*1536;
  const _Float16* fl0 = fe_f + ((long)b*NN + c0 + 2*pr0)*FEAT;
  long cl0 = ((long)b*NN + c0 + 2*pr0)*FEAT;
  long po0 = ((long)b*NN + p0 + pr0)*FEAT;
  long so = ((long)b*128 + r2)*FEAT;
  #pragma unroll
  for (int e = 0; e < 2; e++){
    int f = t + e*256;
    float cs0 = sigm((float)fl0[f])*c[cl0+f] + sigm((float)fl0[FEAT+f])*c[cl0+FEAT+f];
    float cn0 = sigm((float)row0[f])*fmaxf((float)row0[2*FEAT+f], 0.f) + cs0;
    _Float16 hn0 = (_Float16)(sigm((float)row0[FEAT+f])*tanhf(cn0));
    c[po0+f] = cn0; h[po0+f] = hn0;
    if (has1){
      const _Float16* row1 = row0 + 1536;
      const _Float16* fl1 = fl0 + 2*FEAT;
      long cl1 = cl0 + 2*FEAT;
      float cs1 = sigm((float)fl1[f])*c[cl1+f] + sigm((float)fl1[FEAT+f])*c[cl1+FEAT+f];
      float cn1 = sigm((float)row1[f])*fmaxf((float)row1[2*FEAT+f], 0.f) + cs1;
      _Float16 hn1 = (_Float16)(sigm((float)row1[FEAT+f])*tanhf(cn1));
      c[po0+FEAT+f] = cn1; h[po0+FEAT+f] = hn1;
      hsum[so+f] = hn0 + hn1;
    }
  }
}

// ---------------- logits[b,i] = dot(h[b,i,:], e_forw[b,:]) ----------------
__global__ void logits_kernel(const _Float16* __restrict__ h,
                              const float* __restrict__ e_forw,
                              float* __restrict__ logits){
  int b = blockIdx.y;
  int wave = threadIdx.x >> 6, lane = threadIdx.x & 63;
  int i = blockIdx.x*4 + wave;
  if (i >= NN) return;
  half8 hv = *(const half8*)(h + ((long)b*NN+i)*FEAT + lane*8);
  const float* ef = e_forw + b*FEAT + lane*8;
  float s = 0.f;
  #pragma unroll
  for (int q = 0; q < 8; q++) s += (float)hv[q]*ef[q];
  #pragma unroll
  for (int off = 32; off > 0; off >>= 1) s += __shfl_down(s, off, 64);
  if (lane == 0) logits[b*NN+i] = s;
}

// ---------------- softmax over nodes + weighted sum -> fp32 out ----------------
__global__ void out_kernel(const _Float16* __restrict__ h,
                           const float* __restrict__ logits,
                           float* __restrict__ out){
  __shared__ float sprob[NN+1];
  __shared__ float red[128];
  int b = blockIdx.x, yc = blockIdx.y, t = threadIdx.x;
  float mx = -1e30f;
  for (int i = t; i < NN; i += 128) mx = fmaxf(mx, logits[b*NN+i]);
  red[t] = mx; __syncthreads();
  for (int s = 64; s > 0; s >>= 1){ if (t < s) red[t] = fmaxf(red[t], red[t+s]); __syncthreads(); }
  mx = red[0]; __syncthreads();
  float sum = 0.f;
  for (int i = t; i < NN; i += 128){ float p = expf(logits[b*NN+i]-mx); sprob[i] = p; sum += p; }
  red[t] = sum; __syncthreads();
  for (int s = 64; s > 0; s >>= 1){ if (t < s) red[t] += red[t+s]; __syncthreads(); }
  float inv = 1.f/red[0];
  __syncthreads();
  int f = yc*128 + t;
  float acc = 0.f;
  for (int i = 0; i < NN; i++) acc += sprob[i]*(float)h[((long)b*NN+i)*FEAT+f];
  out[b*FEAT+f] = acc*inv;   // OUTPUT IS FP32
}

extern "C" void kernel_launch(void* const* d_in, const int* in_sizes, int n_in,
                              void* d_out, int out_size, void* d_ws, size_t ws_size,
                              hipStream_t stream){
  (void)in_sizes; (void)n_in; (void)out_size; (void)ws_size;
  const void* feat_raw   = d_in[0];
  const int*  finlist    = (const int*)d_in[4];
  const void* eh_raw     = d_in[5];
  const void* Wln_raw    = d_in[6];
  const void* Wlf_raw    = d_in[7];
  const void* Wiou_raw   = d_in[8];
  const void* Wfeiou_raw = d_in[9];
  const void* bfeiou_raw = d_in[10];
  const void* Wf_raw     = d_in[11];
  const void* Wfef_raw   = d_in[12];
  const void* bfef_raw   = d_in[13];

  char* ws = (char*)d_ws;
  size_t off = 0;
  auto alloc = [&](size_t bytes)->char*{
    char* p = ws + off; off += (bytes + 255) & ~(size_t)255; return p;
  };
  int*      flag     = (int*)alloc(256);
  _Float16* feat_h   = (_Float16*)alloc((size_t)NFEAT*2);   // reused as fe_f after feat2_kernel
  _Float16* Wiou_h   = (_Float16*)alloc((size_t)1536*512*2);
  _Float16* Wfeiou_h = (_Float16*)alloc((size_t)1536*512*2);
  _Float16* Wf_h     = (_Float16*)alloc((size_t)512*512*2);
  _Float16* Wfef_h   = (_Float16*)alloc((size_t)512*512*2);
  _Float16* eh_h     = (_Float16*)alloc((size_t)32*1024*2);
  _Float16* Wln_h    = (_Float16*)alloc((size_t)512*1024*2);
  _Float16* Wlf_h    = (_Float16*)alloc((size_t)512*1024*2);
  float*    bfeiou_f = (float*)alloc((size_t)1536*4);
  float*    bfef_f   = (float*)alloc((size_t)512*4);
  float*    e_node   = (float*)alloc((size_t)32*512*4);
  float*    e_forw   = (float*)alloc((size_t)32*512*4);
  _Float16* feat2    = (_Float16*)alloc((size_t)NFEAT*2);
  _Float16* h_half   = (_Float16*)alloc((size_t)NFEAT*2);
  float*    c_buf    = (float*)alloc((size_t)NFEAT*4);
  _Float16* fe_iou   = (_Float16*)alloc((size_t)32*NN*1536*2);  // 50.2 MB
  _Float16* hsum     = (_Float16*)alloc((size_t)32*128*512*2);  // 4 MB
  float*    logits   = (float*)alloc((size_t)32*NN*4);
  _Float16* fe_f     = feat_h;   // overlay: feat_h dead after feat2_kernel

  detect_kernel<<<dim3(1), 256, 0, stream>>>((const unsigned short*)feat_raw, flag);

  cvt_all<<<dim3(5641), 256, 0, stream>>>(
      feat_raw, Wiou_raw, Wfeiou_raw, Wf_raw, Wfef_raw, eh_raw, Wln_raw, Wlf_raw,
      bfeiou_raw, bfef_raw,
      feat_h, Wiou_h, Wfeiou_h, Wf_h, Wfef_h, eh_h, Wln_h, Wlf_h,
      bfeiou_f, bfef_f, flag);

  e_mfma<<<dim3(64), 64, 0, stream>>>(eh_h, Wln_h, Wlf_h, e_node, e_forw);
  feat2_kernel<<<dim3(NN,32), 64, 0, stream>>>(feat_h, finlist, e_node, feat2);

  fe_gemm<<<dim3(128, 32), 256, 0, stream>>>(
      feat2, Wfeiou_h, Wfef_h, bfeiou_f, bfef_f, fe_iou, fe_f);

  pw_leaf<<<dim3(128,32), 256, 0, stream>>>(fe_iou, c_buf, h_half, hsum);

  for (int n = 1; n <= 3; n++){
    int P = 1 << (8-n);       // 128, 64, 32
    int lp = 8 - n;
    int p0 = P - 1, c0 = 2*P - 1;
    int rt = (32*P + 127)/128;
    gemm_level_staged<<<dim3(rt, 40), 256, 0, stream>>>(P, lp,
        h_half, hsum, Wiou_h, Wf_h, fe_iou, fe_f);
    pw_level<<<dim3((P+1)/2,32), 256, 0, stream>>>(fe_iou, fe_f, c_buf, h_half, hsum, P, p0, c0);
  }

  // fused tail: levels P = 16, 8, 4, 2, 1 in one launch (one block per batch)
  tail_levels<<<dim3(32), 1024, 0, stream>>>(
      Wiou_h, Wf_h, fe_iou, fe_f, c_buf, h_half, hsum);

  logits_kernel<<<dim3(128,32), 256, 0, stream>>>(h_half, e_forw, logits);
  out_kernel<<<dim3(32,4), 128, 0, stream>>>(h_half, logits, (float*)d_out);
}

// Round 13
// 389.842 us; speedup vs baseline: 2.1171x; 2.1171x over previous
//
#include <hip/hip_runtime.h>
#include <hip/hip_bf16.h>

#define BATCH 32
#define NN 511
#define FEAT 512
#define NFEAT ((long)32*NN*FEAT)   // 8372224

typedef _Float16 half8 __attribute__((ext_vector_type(8)));
typedef float f32x4 __attribute__((ext_vector_type(4)));

__device__ __forceinline__ float bf2f(unsigned short u){
  union { unsigned int i; float f; } v; v.i = ((unsigned int)u) << 16; return v.f;
}
__device__ __forceinline__ float sigm(float x){ return 1.0f/(1.0f+expf(-x)); }
__device__ __forceinline__ float ldf(const void* p, long i, int f32){
  return f32 ? ((const float*)p)[i] : bf2f(((const unsigned short*)p)[i]);
}
__device__ __forceinline__ void gload_lds16(const _Float16* g, _Float16* l){
  __builtin_amdgcn_global_load_lds(
      (const __attribute__((address_space(1))) unsigned int*)g,
      (__attribute__((address_space(3))) unsigned int*)l, 16, 0, 0);
}

// ---------------- dtype probe: 0 = bf16, 1 = fp32 ----------------
__global__ void detect_kernel(const unsigned short* __restrict__ p, int* __restrict__ flag){
  __shared__ int cnt;
  if (threadIdx.x == 0) cnt = 0;
  __syncthreads();
  int local = 0;
  for (int i = threadIdx.x; i < 4096; i += 256){
    unsigned short u = p[2*i];
    int e = (u >> 7) & 0xFF;
    if (u != 0 && e >= 117 && e <= 133) local++;
  }
  atomicAdd(&cnt, local);
  __syncthreads();
  if (threadIdx.x == 0) *flag = (cnt > 2048) ? 0 : 1;
}

// ---------------- single fused conversion kernel ----------------
__global__ void cvt_all(
    const void* __restrict__ feat, const void* __restrict__ Wiou,
    const void* __restrict__ Wfeiou, const void* __restrict__ Wf,
    const void* __restrict__ Wfef, const void* __restrict__ eh,
    const void* __restrict__ Wln, const void* __restrict__ Wlf,
    const void* __restrict__ biou, const void* __restrict__ bfv,
    _Float16* __restrict__ feat_h, _Float16* __restrict__ Wiou_h,
    _Float16* __restrict__ Wfeiou_h, _Float16* __restrict__ Wf_h,
    _Float16* __restrict__ Wfef_h, _Float16* __restrict__ eh_h,
    _Float16* __restrict__ Wln_h, _Float16* __restrict__ Wlf_h,
    float* __restrict__ biou_f, float* __restrict__ bf_f,
    const int* __restrict__ flag)
{
  long g = ((long)blockIdx.x*256 + threadIdx.x)*8;
  int f32 = *flag;
  const long S1 = NFEAT;            // feat
  const long S2 = S1 + 786432;      // Wiou
  const long S3 = S2 + 786432;      // Wfeiou
  const long S4 = S3 + 262144;      // Wf
  const long S5 = S4 + 262144;      // Wfef
  const long S6 = S5 + 32768;       // eh
  const long S7 = S6 + 524288;      // Wln
  const long S8 = S7 + 524288;      // Wlf  (= 11550720)
  const long S9 = S8 + 1536;        // bias iou (fp32 out)
  const long SA = S9 + 512;         // bias f
  if (g >= SA) return;
  if (g >= S9){
    long o = g - S9;
    for (int q = 0; q < 8; q++) bf_f[o+q] = ldf(bfv, o+q, f32);
    return;
  }
  if (g >= S8){
    long o = g - S8;
    for (int q = 0; q < 8; q++) biou_f[o+q] = ldf(biou, o+q, f32);
    return;
  }
  const void* src; _Float16* dst; long off;
  if      (g < S1){ src=feat;   dst=feat_h;   off=g; }
  else if (g < S2){ src=Wiou;   dst=Wiou_h;   off=g-S1; }
  else if (g < S3){ src=Wfeiou; dst=Wfeiou_h; off=g-S2; }
  else if (g < S4){ src=Wf;     dst=Wf_h;     off=g-S3; }
  else if (g < S5){ src=Wfef;   dst=Wfef_h;   off=g-S4; }
  else if (g < S6){ src=eh;     dst=eh_h;     off=g-S5; }
  else if (g < S7){ src=Wln;    dst=Wln_h;    off=g-S6; }
  else            { src=Wlf;    dst=Wlf_h;    off=g-S7; }
  #pragma unroll
  for (int q = 0; q < 8; q++) dst[off+q] = (_Float16)ldf(src, off+q, f32);
}

// ---------------- e_node/e_forw via MFMA ----------------
__global__ __launch_bounds__(64) void e_mfma(
    const _Float16* __restrict__ eh,
    const _Float16* __restrict__ Wn,
    const _Float16* __restrict__ Wf,
    float* __restrict__ e_node, float* __restrict__ e_forw)
{
  int lane = threadIdx.x;
  int m = lane & 15, quad = lane >> 4;
  int n = blockIdx.x*16 + m;
  const _Float16* wrow = (n < 512) ? (Wn + (long)n*1024) : (Wf + (long)(n-512)*1024);
  f32x4 acc[2] = {};
  for (int ks = 0; ks < 32; ks++){
    int kk = ks*32 + quad*8;
    half8 bfr = *(const half8*)(wrow + kk);
    #pragma unroll
    for (int i = 0; i < 2; i++){
      half8 afr = *(const half8*)(eh + (long)(i*16 + m)*1024 + kk);
      acc[i] = __builtin_amdgcn_mfma_f32_16x16x32_f16(afr, bfr, acc[i], 0, 0, 0);
    }
  }
  float* dst = (n < 512) ? e_node : e_forw;
  int col = (n < 512) ? n : (n - 512);
  #pragma unroll
  for (int i = 0; i < 2; i++)
    #pragma unroll
    for (int reg = 0; reg < 4; reg++){
      int b = i*16 + quad*4 + reg;
      dst[b*FEAT + col] = acc[i][reg];
    }
}

// ---------------- feat2: one wave per (node,batch); fully vectorized ---------------
__global__ __launch_bounds__(64) void feat2_kernel(
    const _Float16* __restrict__ feat,
    const int* __restrict__ finlist,
    const float* __restrict__ e_node,
    _Float16* __restrict__ feat2){
  int i = blockIdx.x, b = blockIdx.y, lane = threadIdx.x;
  int s0 = finlist[(b*NN+i)*2+0];
  int e0 = finlist[(b*NN+i)*2+1];
  s0 = min(max(s0, 0), NN-1);
  e0 = min(max(e0, s0), NN-1);
  int w = min(e0 - s0 + 1, 4);

  const _Float16* base = feat + ((long)b*NN + s0)*FEAT + lane*8;
  half8 v[4];
  #pragma unroll
  for (int q = 0; q < 4; q++){
    if (q < w) v[q] = *(const half8*)(base + (long)q*FEAT);
    else       v[q] = half8{};
  }
  const float* ep = e_node + b*FEAT + lane*8;
  f32x4 ev0 = *(const f32x4*)ep;
  f32x4 ev1 = *(const f32x4*)(ep+4);
  float en[8] = {ev0[0],ev0[1],ev0[2],ev0[3],ev1[0],ev1[1],ev1[2],ev1[3]};

  float s[4];
  #pragma unroll
  for (int q = 0; q < 4; q++){
    float acc = 0.f;
    #pragma unroll
    for (int j = 0; j < 8; j++) acc += (float)v[q][j]*en[j];
    s[q] = acc;
  }
  #pragma unroll
  for (int q = 0; q < 4; q++)
    #pragma unroll
    for (int off = 1; off < 64; off <<= 1)
      s[q] += __shfl_xor(s[q], off, 64);

  float mx = -1e30f;
  #pragma unroll
  for (int q = 0; q < 4; q++){
    if (q >= w) s[q] = -1e30f;
    mx = fmaxf(mx, s[q]);
  }
  float p[4]; float den = 0.f;
  #pragma unroll
  for (int q = 0; q < 4; q++){ p[q] = (q < w) ? expf(s[q]-mx) : 0.f; den += p[q]; }
  float inv = 1.f/den;

  half8 o;
  #pragma unroll
  for (int j = 0; j < 8; j++){
    float acc = 0.f;
    #pragma unroll
    for (int q = 0; q < 4; q++) acc += p[q]*(float)v[q][j];
    o[j] = (_Float16)(acc*inv);
  }
  *(half8*)(feat2 + ((long)b*NN + i)*FEAT + lane*8) = o;
}

// ---------------- fe GEMM: LDS-staged, double-buffered (verified R9/R10) ----------
__global__ __launch_bounds__(256) void fe_gemm(
    const _Float16* __restrict__ feat2,
    const _Float16* __restrict__ Wfeiou, const _Float16* __restrict__ Wfef,
    const float* __restrict__ biou, const float* __restrict__ bf,
    _Float16* __restrict__ fe_iou, _Float16* __restrict__ fe_f)
{
  __shared__ _Float16 Abuf[2][128*64];
  __shared__ _Float16 Bbuf[2][64*64];
  const int MT = 32*NN;                // 16352
  int tid = threadIdx.x;
  int wv = tid >> 6, lane = tid & 63;
  int m = lane & 15, quad = lane >> 4;
  int cg = blockIdx.y;
  int rowbase = blockIdx.x*128;
  int which = (cg < 24) ? 0 : 1;
  int colbase = which ? (cg-24)*64 : cg*64;
  const _Float16* W = which ? Wfef : Wfeiou;

  const _Float16* gA[4];
  {
    #pragma unroll
    for (int t = 0; t < 4; t++){
      int c = wv*64 + lane + t*256;
      int rt = c >> 3, kc = c & 7;
      int r = rowbase + rt; if (r >= MT) r = MT - 1;
      int bb = r / NN, node = r - bb*NN;
      int srcn = which ? ((node >= 1) ? ((node-1)>>1) : 0) : node;
      gA[t] = feat2 + ((long)bb*NN + srcn)*FEAT + ((kc ^ (rt & 7))<<3);
    }
  }
  const _Float16* gB[2];
  {
    #pragma unroll
    for (int t = 0; t < 2; t++){
      int c = wv*64 + lane + t*256;
      int rt = c >> 3, kc = c & 7;
      gB[t] = W + (long)(colbase + rt)*FEAT + ((kc ^ (rt & 7))<<3);
    }
  }

  int aoff[2][2], boff[4][2];
  #pragma unroll
  for (int i = 0; i < 2; i++)
    #pragma unroll
    for (int ks = 0; ks < 2; ks++){
      int rt = wv*32 + i*16 + m;
      aoff[i][ks] = rt*128 + (((ks*4 + quad) ^ (rt & 7))<<4);
    }
  #pragma unroll
  for (int j = 0; j < 4; j++)
    #pragma unroll
    for (int ks = 0; ks < 2; ks++){
      int rt = j*16 + m;
      boff[j][ks] = rt*128 + (((ks*4 + quad) ^ (rt & 7))<<4);
    }

  f32x4 acc[2][4] = {};

  #pragma unroll
  for (int t = 0; t < 4; t++)
    gload_lds16(gA[t], &Abuf[0][(wv*64 + t*256)*8]);
  #pragma unroll
  for (int t = 0; t < 2; t++)
    gload_lds16(gB[t], &Bbuf[0][(wv*64 + t*256)*8]);

  for (int it = 0; it < 8; ++it){
    int cur = it & 1;
    __syncthreads();
    if (it < 7){
      int kk = (it+1)*64;
      #pragma unroll
      for (int t = 0; t < 4; t++)
        gload_lds16(gA[t] + kk, &Abuf[cur^1][(wv*64 + t*256)*8]);
      #pragma unroll
      for (int t = 0; t < 2; t++)
        gload_lds16(gB[t] + kk, &Bbuf[cur^1][(wv*64 + t*256)*8]);
    }
    const char* Ab_ = (const char*)&Abuf[cur][0];
    const char* Bb_ = (const char*)&Bbuf[cur][0];
    #pragma unroll
    for (int ks = 0; ks < 2; ks++){
      half8 a0 = *(const half8*)(Ab_ + aoff[0][ks]);
      half8 a1 = *(const half8*)(Ab_ + aoff[1][ks]);
      #pragma unroll
      for (int j = 0; j < 4; j++){
        half8 bfr = *(const half8*)(Bb_ + boff[j][ks]);
        acc[0][j] = __builtin_amdgcn_mfma_f32_16x16x32_f16(a0, bfr, acc[0][j], 0, 0, 0);
        acc[1][j] = __builtin_amdgcn_mfma_f32_16x16x32_f16(a1, bfr, acc[1][j], 0, 0, 0);
      }
    }
  }
  __syncthreads();

  const float* bias = which ? bf : biou;
  float bs[4];
  #pragma unroll
  for (int j = 0; j < 4; j++) bs[j] = bias[colbase + j*16 + m];

  _Float16* sl = &Abuf[0][wv*16*72];
  int lr = lane >> 2;
  int lc = (lane & 3) * 16;
  #pragma unroll
  for (int i = 0; i < 2; i++){
    #pragma unroll
    for (int j = 0; j < 4; j++)
      #pragma unroll
      for (int reg = 0; reg < 4; reg++)
        sl[(quad*4+reg)*72 + j*16 + m] = (_Float16)(acc[i][j][reg] + bs[j]);
    half8 o0 = *(const half8*)&sl[lr*72 + lc];
    half8 o1 = *(const half8*)&sl[lr*72 + lc + 8];
    int r = rowbase + wv*32 + i*16 + lr;
    if (r < MT){
      int b = r / NN, node = r - b*NN;
      if (which == 0){
        _Float16* dst = fe_iou + ((long)b*NN + node)*1536 + colbase + lc;
        *(half8*)dst = o0; *(half8*)(dst+8) = o1;
      } else if (node >= 1){
        _Float16* dst = fe_f + ((long)b*NN + node)*FEAT + colbase + lc;
        *(half8*)dst = o0; *(half8*)(dst+8) = o1;
      }
    }
  }
}

// ---------------- staged per-level GEMM (P>=32, verified R10) ---------
__global__ __launch_bounds__(256) void gemm_level_staged(
    int P, int lp,
    const _Float16* __restrict__ hbuf, const _Float16* __restrict__ hsum,
    const _Float16* __restrict__ Wiou, const _Float16* __restrict__ Wf,
    _Float16* __restrict__ fe_iou, _Float16* __restrict__ fe_f)
{
  __shared__ _Float16 Abuf[2][128*64];
  __shared__ _Float16 Bbuf[2][64*64];
  int Mtot = P << 5;
  int tid = threadIdx.x;
  int wv = tid >> 6, lane = tid & 63;
  int m = lane & 15, quad = lane >> 4;
  int cg = blockIdx.y;
  int rowbase = blockIdx.x*128;
  int p0 = P - 1, c0 = 2*P - 1;
  int which, colbase;
  if (cg < 24)      { which = 0; colbase = cg*64; }
  else if (cg < 32) { which = 1; colbase = (cg-24)*64; }
  else              { which = 2; colbase = (cg-32)*64; }
  const _Float16* W = (which == 0) ? Wiou : Wf;

  const _Float16* gA[4];
  {
    #pragma unroll
    for (int t = 0; t < 4; t++){
      int c = wv*64 + lane + t*256;
      int rt = c >> 3, kc = c & 7;
      int r = rowbase + rt; if (r >= Mtot) r = Mtot - 1;
      int bb = r >> lp, p = r & (P-1);
      const _Float16* base;
      if (which == 0) base = hsum + ((long)bb*128 + p)*FEAT;
      else            base = hbuf + ((long)bb*NN + c0 + 2*p + (which==2))*FEAT;
      gA[t] = base + ((kc ^ (rt & 7))<<3);
    }
  }
  const _Float16* gB[2];
  {
    #pragma unroll
    for (int t = 0; t < 2; t++){
      int c = wv*64 + lane + t*256;
      int rt = c >> 3, kc = c & 7;
      gB[t] = W + (long)(colbase + rt)*FEAT + ((kc ^ (rt & 7))<<3);
    }
  }

  int aoff[2][2], boff[4][2];
  #pragma unroll
  for (int i = 0; i < 2; i++)
    #pragma unroll
    for (int ks = 0; ks < 2; ks++){
      int rt = wv*32 + i*16 + m;
      aoff[i][ks] = rt*128 + (((ks*4 + quad) ^ (rt & 7))<<4);
    }
  #pragma unroll
  for (int j = 0; j < 4; j++)
    #pragma unroll
    for (int ks = 0; ks < 2; ks++){
      int rt = j*16 + m;
      boff[j][ks] = rt*128 + (((ks*4 + quad) ^ (rt & 7))<<4);
    }

  f32x4 acc[2][4] = {};

  #pragma unroll
  for (int t = 0; t < 4; t++)
    gload_lds16(gA[t], &Abuf[0][(wv*64 + t*256)*8]);
  #pragma unroll
  for (int t = 0; t < 2; t++)
    gload_lds16(gB[t], &Bbuf[0][(wv*64 + t*256)*8]);

  for (int it = 0; it < 8; ++it){
    int cur = it & 1;
    __syncthreads();
    if (it < 7){
      int kk = (it+1)*64;
      #pragma unroll
      for (int t = 0; t < 4; t++)
        gload_lds16(gA[t] + kk, &Abuf[cur^1][(wv*64 + t*256)*8]);
      #pragma unroll
      for (int t = 0; t < 2; t++)
        gload_lds16(gB[t] + kk, &Bbuf[cur^1][(wv*64 + t*256)*8]);
    }
    const char* Ab_ = (const char*)&Abuf[cur][0];
    const char* Bb_ = (const char*)&Bbuf[cur][0];
    #pragma unroll
    for (int ks = 0; ks < 2; ks++){
      half8 a0 = *(const half8*)(Ab_ + aoff[0][ks]);
      half8 a1 = *(const half8*)(Ab_ + aoff[1][ks]);
      #pragma unroll
      for (int j = 0; j < 4; j++){
        half8 bfr = *(const half8*)(Bb_ + boff[j][ks]);
        acc[0][j] = __builtin_amdgcn_mfma_f32_16x16x32_f16(a0, bfr, acc[0][j], 0, 0, 0);
        acc[1][j] = __builtin_amdgcn_mfma_f32_16x16x32_f16(a1, bfr, acc[1][j], 0, 0, 0);
      }
    }
  }
  __syncthreads();

  float* fsl = (float*)((char*)&Abuf[0][0] + wv*(16*68*4));
  int lr = lane >> 2;
  int lc = (lane & 3) * 16;
  #pragma unroll
  for (int i = 0; i < 2; i++){
    #pragma unroll
    for (int j = 0; j < 4; j++)
      #pragma unroll
      for (int reg = 0; reg < 4; reg++)
        fsl[(quad*4+reg)*68 + j*16 + m] = acc[i][j][reg];
    f32x4 a0 = *(const f32x4*)&fsl[lr*68 + lc];
    f32x4 a1 = *(const f32x4*)&fsl[lr*68 + lc + 4];
    f32x4 a2 = *(const f32x4*)&fsl[lr*68 + lc + 8];
    f32x4 a3 = *(const f32x4*)&fsl[lr*68 + lc + 12];
    int r = rowbase + wv*32 + i*16 + lr;
    if (r < Mtot){
      int b = r >> lp, p = r & (P-1);
      _Float16* dst;
      if (which == 0) dst = fe_iou + ((long)b*NN + p0 + p)*1536 + colbase + lc;
      else            dst = fe_f  + ((long)b*NN + c0 + 2*p + (which-1))*FEAT + colbase + lc;
      half8 f0 = *(const half8*)dst;
      half8 f1 = *(const half8*)(dst+8);
      half8 o0, o1;
      #pragma unroll
      for (int q = 0; q < 4; q++){
        o0[q]   = (_Float16)(a0[q] + (float)f0[q]);
        o0[q+4] = (_Float16)(a1[q] + (float)f0[q+4]);
        o1[q]   = (_Float16)(a2[q] + (float)f1[q]);
        o1[q+4] = (_Float16)(a3[q] + (float)f1[q+4]);
      }
      *(half8*)dst = o0; *(half8*)(dst+8) = o1;
    }
  }
}

// ---------------- per-level GEMM, one-wave form (P<=16) ----------
__global__ __launch_bounds__(64) void gemm_level_h(
    int P, int lp,
    const _Float16* __restrict__ hbuf,
    const _Float16* __restrict__ Wiou, const _Float16* __restrict__ Wf,
    _Float16* __restrict__ fe_iou, _Float16* __restrict__ fe_f)
{
  __shared__ float ldsf[16*64];
  int lane = threadIdx.x;
  int m = lane & 15, quad = lane >> 4;
  int cg = blockIdx.y;
  int Mtot = P << 5;
  int rowbase = blockIdx.x*64;
  if (rowbase >= Mtot) return;
  int p0 = P - 1, c0 = 2*P - 1;

  int which, colbase;
  if (cg < 24)      { which = 0; colbase = cg*64; }
  else if (cg < 32) { which = 1; colbase = (cg-24)*64; }
  else              { which = 2; colbase = (cg-32)*64; }

  const _Float16* W = (which == 0) ? Wiou : Wf;
  bool dual = (which == 0);

  f32x4 acc[4][4] = {};
  const _Float16* ap[4];
  const _Float16* wp[4];
  #pragma unroll
  for (int i = 0; i < 4; i++){
    int r = rowbase + i*16 + m;
    if (r >= Mtot) r = Mtot - 1;
    int b = r >> lp, p = r & (P-1);
    int node = c0 + 2*p + ((which == 2) ? 1 : 0);
    ap[i] = hbuf + ((long)b*NN + node)*FEAT + quad*8;
    wp[i] = W + (long)(colbase + i*16 + m)*FEAT + quad*8;
  }

  half8 Ab[3][4], A2b[3][4], Bb[3][4];
  #pragma unroll
  for (int s = 0; s < 2; s++){
    long kk = (long)s*32;
    #pragma unroll
    for (int i = 0; i < 4; i++){
      Ab[s][i] = *(const half8*)(ap[i] + kk);
      if (dual) A2b[s][i] = *(const half8*)(ap[i] + FEAT + kk);
      Bb[s][i] = *(const half8*)(wp[i] + kk);
    }
  }
  #pragma unroll
  for (int ks = 0; ks < 16; ++ks){
    int cur = ks % 3;
    if (ks + 2 < 16){
      int nxt = (ks + 2) % 3;
      long kk = (long)(ks + 2)*32;
      #pragma unroll
      for (int i = 0; i < 4; i++){
        Ab[nxt][i] = *(const half8*)(ap[i] + kk);
        if (dual) A2b[nxt][i] = *(const half8*)(ap[i] + FEAT + kk);
        Bb[nxt][i] = *(const half8*)(wp[i] + kk);
      }
    }
    half8 av[4];
    #pragma unroll
    for (int i = 0; i < 4; i++){
      av[i] = Ab[cur][i];
      if (dual) av[i] = av[i] + A2b[cur][i];
    }
    #pragma unroll
    for (int i = 0; i < 4; i++)
      #pragma unroll
      for (int j = 0; j < 4; j++)
        acc[i][j] = __builtin_amdgcn_mfma_f32_16x16x32_f16(av[i], Bb[cur][j], acc[i][j], 0, 0, 0);
  }

  int lr = lane >> 2;
  int lc = (lane & 3) * 16;
  #pragma unroll
  for (int i = 0; i < 4; i++){
    #pragma unroll
    for (int j = 0; j < 4; j++)
      #pragma unroll
      for (int reg = 0; reg < 4; reg++)
        ldsf[(quad*4+reg)*64 + j*16 + m] = acc[i][j][reg];
    __syncthreads();
    f32x4 a0 = *(const f32x4*)&ldsf[lr*64 + lc];
    f32x4 a1 = *(const f32x4*)&ldsf[lr*64 + lc + 4];
    f32x4 a2 = *(const f32x4*)&ldsf[lr*64 + lc + 8];
    f32x4 a3 = *(const f32x4*)&ldsf[lr*64 + lc + 12];
    int r = rowbase + i*16 + lr;
    if (r < Mtot){
      int b = r >> lp, p = r & (P-1);
      _Float16* dst;
      if (which == 0) dst = fe_iou + ((long)b*NN + p0 + p)*1536 + colbase + lc;
      else            dst = fe_f  + ((long)b*NN + c0 + 2*p + (which-1))*FEAT + colbase + lc;
      half8 f0 = *(const half8*)dst;
      half8 f1 = *(const half8*)(dst+8);
      half8 o0, o1;
      #pragma unroll
      for (int q = 0; q < 4; q++){
        o0[q]   = (_Float16)(a0[q] + (float)f0[q]);
        o0[q+4] = (_Float16)(a1[q] + (float)f0[q+4]);
        o1[q]   = (_Float16)(a2[q] + (float)f1[q]);
        o1[q+4] = (_Float16)(a3[q] + (float)f1[q+4]);
      }
      *(half8*)dst = o0; *(half8*)(dst+8) = o1;
    }
    __syncthreads();
  }
}

// ---------------- level-0 pointwise (leaves), paired, + hsum (verified R10) ------
__global__ void pw_leaf(const _Float16* __restrict__ fe_iou, float* __restrict__ c,
                        _Float16* __restrict__ h, _Float16* __restrict__ hsum){
  int r2 = blockIdx.x, b = blockIdx.y, t = threadIdx.x;   // r2 < 128
  int l0 = 255 + 2*r2;
  const _Float16* row0 = fe_iou + ((long)b*NN + l0)*1536;
  const _Float16* row1 = row0 + 1536;
  long off0 = ((long)b*NN + l0)*FEAT;
  long off1 = off0 + FEAT;
  long so = ((long)b*128 + r2)*FEAT;
  #pragma unroll
  for (int e = 0; e < 2; e++){
    int f = t + e*256;
    float cn0 = sigm((float)row0[f])*fmaxf((float)row0[2*FEAT+f], 0.f);
    _Float16 hn0 = (_Float16)(sigm((float)row0[FEAT+f])*tanhf(cn0));
    float cn1 = sigm((float)row1[f])*fmaxf((float)row1[2*FEAT+f], 0.f);
    _Float16 hn1 = (_Float16)(sigm((float)row1[FEAT+f])*tanhf(cn1));
    c[off0+f] = cn0; h[off0+f] = hn0;
    c[off1+f] = cn1; h[off1+f] = hn1;
    hsum[so+f] = hn0 + hn1;
  }
}

// ---------------- level-n pointwise, paired, + hsum (verified R10) ----------------
__global__ void pw_level(const _Float16* __restrict__ fe_iou, const _Float16* __restrict__ fe_f,
                         float* __restrict__ c, _Float16* __restrict__ h,
                         _Float16* __restrict__ hsum,
                         int P, int p0, int c0){
  int r2 = blockIdx.x, b = blockIdx.y, t = threadIdx.x;
  int pr0 = 2*r2, pr1 = 2*r2 + 1;
  bool has1 = (pr1 < P);
  const _Float16* row0 = fe_iou + ((long)b*NN + p0 + pr0)*1536;
  const _Float16* fl0 = fe_f + ((long)b*NN + c0 + 2*pr0)*FEAT;
  long cl0 = ((long)b*NN + c0 + 2*pr0)*FEAT;
  long po0 = ((long)b*NN + p0 + pr0)*FEAT;
  long so = ((long)b*128 + r2)*FEAT;
  #pragma unroll
  for (int e = 0; e < 2; e++){
    int f = t + e*256;
    float cs0 = sigm((float)fl0[f])*c[cl0+f] + sigm((float)fl0[FEAT+f])*c[cl0+FEAT+f];
    float cn0 = sigm((float)row0[f])*fmaxf((float)row0[2*FEAT+f], 0.f) + cs0;
    _Float16 hn0 = (_Float16)(sigm((float)row0[FEAT+f])*tanhf(cn0));
    c[po0+f] = cn0; h[po0+f] = hn0;
    if (has1){
      const _Float16* row1 = row0 + 1536;
      const _Float16* fl1 = fl0 + 2*FEAT;
      long cl1 = cl0 + 2*FEAT;
      float cs1 = sigm((float)fl1[f])*c[cl1+f] + sigm((float)fl1[FEAT+f])*c[cl1+FEAT+f];
      float cn1 = sigm((float)row1[f])*fmaxf((float)row1[2*FEAT+f], 0.f) + cs1;
      _Float16 hn1 = (_Float16)(sigm((float)row1[FEAT+f])*tanhf(cn1));
      c[po0+FEAT+f] = cn1; h[po0+FEAT+f] = hn1;
      hsum[so+f] = hn0 + hn1;
    }
  }
}

// ---------------- logits[b,i] = dot(h[b,i,:], e_forw[b,:]) ----------------
__global__ void logits_kernel(const _Float16* __restrict__ h,
                              const float* __restrict__ e_forw,
                              float* __restrict__ logits){
  int b = blockIdx.y;
  int wave = threadIdx.x >> 6, lane = threadIdx.x & 63;
  int i = blockIdx.x*4 + wave;
  if (i >= NN) return;
  half8 hv = *(const half8*)(h + ((long)b*NN+i)*FEAT + lane*8);
  const float* ef = e_forw + b*FEAT + lane*8;
  float s = 0.f;
  #pragma unroll
  for (int q = 0; q < 8; q++) s += (float)hv[q]*ef[q];
  #pragma unroll
  for (int off = 32; off > 0; off >>= 1) s += __shfl_down(s, off, 64);
  if (lane == 0) logits[b*NN+i] = s;
}

// ---------------- softmax + weighted sum, vectorized: grid (32,8) x 64 ----------
// lane = sub*8 + k: sub (0..7) splits the node range; k picks features
// fl = k*8 within this block's 64-col slice. half8 loads -> coalesced 1KB/wave.
__global__ __launch_bounds__(64) void out_kernel(
    const _Float16* __restrict__ h,
    const float* __restrict__ logits,
    float* __restrict__ out){
  __shared__ float sprob[NN+1];
  int b = blockIdx.x, yc = blockIdx.y, lane = threadIdx.x;
  float mx = -1e30f;
  for (int i = lane; i < NN; i += 64) mx = fmaxf(mx, logits[b*NN+i]);
  #pragma unroll
  for (int off = 32; off > 0; off >>= 1) mx = fmaxf(mx, __shfl_xor(mx, off, 64));
  float sum = 0.f;
  for (int i = lane; i < NN; i += 64){
    float p = expf(logits[b*NN+i]-mx);
    sprob[i] = p; sum += p;
  }
  #pragma unroll
  for (int off = 32; off > 0; off >>= 1) sum += __shfl_xor(sum, off, 64);
  float inv = 1.f/sum;
  __syncthreads();

  int sub = lane >> 3;            // node-range split
  int fl  = (lane & 7) * 8;       // feature offset in 64-col slice
  const _Float16* hp = h + (long)b*NN*FEAT + yc*64 + fl;
  float acc[8] = {};
  for (int i = sub; i < NN; i += 8){
    float p = sprob[i];
    half8 hv = *(const half8*)(hp + (long)i*FEAT);
    #pragma unroll
    for (int q = 0; q < 8; q++) acc[q] += p*(float)hv[q];
  }
  #pragma unroll
  for (int q = 0; q < 8; q++){
    #pragma unroll
    for (int off = 8; off < 64; off <<= 1)
      acc[q] += __shfl_xor(acc[q], off, 64);
  }
  if (sub == 0){
    float* dst = out + b*FEAT + yc*64 + fl;
    #pragma unroll
    for (int q = 0; q < 8; q++) dst[q] = acc[q]*inv;
  }
}

extern "C" void kernel_launch(void* const* d_in, const int* in_sizes, int n_in,
                              void* d_out, int out_size, void* d_ws, size_t ws_size,
                              hipStream_t stream){
  (void)in_sizes; (void)n_in; (void)out_size; (void)ws_size;
  const void* feat_raw   = d_in[0];
  const int*  finlist    = (const int*)d_in[4];
  const void* eh_raw     = d_in[5];
  const void* Wln_raw    = d_in[6];
  const void* Wlf_raw    = d_in[7];
  const void* Wiou_raw   = d_in[8];
  const void* Wfeiou_raw = d_in[9];
  const void* bfeiou_raw = d_in[10];
  const void* Wf_raw     = d_in[11];
  const void* Wfef_raw   = d_in[12];
  const void* bfef_raw   = d_in[13];

  char* ws = (char*)d_ws;
  size_t off = 0;
  auto alloc = [&](size_t bytes)->char*{
    char* p = ws + off; off += (bytes + 255) & ~(size_t)255; return p;
  };
  int*      flag     = (int*)alloc(256);
  _Float16* feat_h   = (_Float16*)alloc((size_t)NFEAT*2);   // reused as fe_f after feat2_kernel
  _Float16* Wiou_h   = (_Float16*)alloc((size_t)1536*512*2);
  _Float16* Wfeiou_h = (_Float16*)alloc((size_t)1536*512*2);
  _Float16* Wf_h     = (_Float16*)alloc((size_t)512*512*2);
  _Float16* Wfef_h   = (_Float16*)alloc((size_t)512*512*2);
  _Float16* eh_h     = (_Float16*)alloc((size_t)32*1024*2);
  _Float16* Wln_h    = (_Float16*)alloc((size_t)512*1024*2);
  _Float16* Wlf_h    = (_Float16*)alloc((size_t)512*1024*2);
  float*    bfeiou_f = (float*)alloc((size_t)1536*4);
  float*    bfef_f   = (float*)alloc((size_t)512*4);
  float*    e_node   = (float*)alloc((size_t)32*512*4);
  float*    e_forw   = (float*)alloc((size_t)32*512*4);
  _Float16* feat2    = (_Float16*)alloc((size_t)NFEAT*2);
  _Float16* h_half   = (_Float16*)alloc((size_t)NFEAT*2);
  float*    c_buf    = (float*)alloc((size_t)NFEAT*4);
  _Float16* fe_iou   = (_Float16*)alloc((size_t)32*NN*1536*2);  // 50.2 MB
  _Float16* hsum     = (_Float16*)alloc((size_t)32*128*512*2);  // 4 MB
  float*    logits   = (float*)alloc((size_t)32*NN*4);
  _Float16* fe_f     = feat_h;   // overlay: feat_h dead after feat2_kernel

  detect_kernel<<<dim3(1), 256, 0, stream>>>((const unsigned short*)feat_raw, flag);

  cvt_all<<<dim3(5641), 256, 0, stream>>>(
      feat_raw, Wiou_raw, Wfeiou_raw, Wf_raw, Wfef_raw, eh_raw, Wln_raw, Wlf_raw,
      bfeiou_raw, bfef_raw,
      feat_h, Wiou_h, Wfeiou_h, Wf_h, Wfef_h, eh_h, Wln_h, Wlf_h,
      bfeiou_f, bfef_f, flag);

  e_mfma<<<dim3(64), 64, 0, stream>>>(eh_h, Wln_h, Wlf_h, e_node, e_forw);
  feat2_kernel<<<dim3(NN,32), 64, 0, stream>>>(feat_h, finlist, e_node, feat2);

  fe_gemm<<<dim3(128, 32), 256, 0, stream>>>(
      feat2, Wfeiou_h, Wfef_h, bfeiou_f, bfef_f, fe_iou, fe_f);

  pw_leaf<<<dim3(128,32), 256, 0, stream>>>(fe_iou, c_buf, h_half, hsum);

  for (int n = 1; n <= 8; n++){
    int P = 1 << (8-n);
    int lp = 8 - n;
    int p0 = P - 1, c0 = 2*P - 1;
    if (P >= 32){
      int rt = (32*P + 127)/128;
      gemm_level_staged<<<dim3(rt, 40), 256, 0, stream>>>(P, lp,
          h_half, hsum, Wiou_h, Wf_h, fe_iou, fe_f);
    } else {
      int gy = (32*P + 63)/64;
      gemm_level_h<<<dim3(gy, 40), 64, 0, stream>>>(P, lp,
          h_half, Wiou_h, Wf_h, fe_iou, fe_f);
    }
    pw_level<<<dim3((P+1)/2,32), 256, 0, stream>>>(fe_iou, fe_f, c_buf, h_half, hsum, P, p0, c0);
  }

  logits_kernel<<<dim3(128,32), 256, 0, stream>>>(h_half, e_forw, logits);
  out_kernel<<<dim3(32,8), 64, 0, stream>>>(h_half, logits, (float*)d_out);
}

// Round 16
// 382.223 us; speedup vs baseline: 2.1593x; 1.0199x over previous
//
#include <hip/hip_runtime.h>
#include <hip/hip_bf16.h>

#define BATCH 32
#define NN 511
#define FEAT 512
#define NFEAT ((long)32*NN*FEAT)   // 8372224

typedef _Float16 half8 __attribute__((ext_vector_type(8)));
typedef float f32x4 __attribute__((ext_vector_type(4)));

__device__ __forceinline__ float bf2f(unsigned short u){
  union { unsigned int i; float f; } v; v.i = ((unsigned int)u) << 16; return v.f;
}
__device__ __forceinline__ float sigm(float x){ return 1.0f/(1.0f+expf(-x)); }
__device__ __forceinline__ float ldf(const void* p, long i, int f32){
  return f32 ? ((const float*)p)[i] : bf2f(((const unsigned short*)p)[i]);
}
__device__ __forceinline__ void gload_lds16(const _Float16* g, _Float16* l){
  __builtin_amdgcn_global_load_lds(
      (const __attribute__((address_space(1))) unsigned int*)g,
      (__attribute__((address_space(3))) unsigned int*)l, 16, 0, 0);
}

// ---------------- dtype probe: 0 = bf16, 1 = fp32 ----------------
__global__ void detect_kernel(const unsigned short* __restrict__ p, int* __restrict__ flag){
  __shared__ int cnt;
  if (threadIdx.x == 0) cnt = 0;
  __syncthreads();
  int local = 0;
  for (int i = threadIdx.x; i < 4096; i += 256){
    unsigned short u = p[2*i];
    int e = (u >> 7) & 0xFF;
    if (u != 0 && e >= 117 && e <= 133) local++;
  }
  atomicAdd(&cnt, local);
  __syncthreads();
  if (threadIdx.x == 0) *flag = (cnt > 2048) ? 0 : 1;
}

// ---------------- single fused conversion kernel ----------------
__global__ void cvt_all(
    const void* __restrict__ feat, const void* __restrict__ Wiou,
    const void* __restrict__ Wfeiou, const void* __restrict__ Wf,
    const void* __restrict__ Wfef, const void* __restrict__ eh,
    const void* __restrict__ Wln, const void* __restrict__ Wlf,
    const void* __restrict__ biou, const void* __restrict__ bfv,
    _Float16* __restrict__ feat_h, _Float16* __restrict__ Wiou_h,
    _Float16* __restrict__ Wfeiou_h, _Float16* __restrict__ Wf_h,
    _Float16* __restrict__ Wfef_h, _Float16* __restrict__ eh_h,
    _Float16* __restrict__ Wln_h, _Float16* __restrict__ Wlf_h,
    float* __restrict__ biou_f, float* __restrict__ bf_f,
    const int* __restrict__ flag)
{
  long g = ((long)blockIdx.x*256 + threadIdx.x)*8;
  int f32 = *flag;
  const long S1 = NFEAT;            // feat
  const long S2 = S1 + 786432;      // Wiou
  const long S3 = S2 + 786432;      // Wfeiou
  const long S4 = S3 + 262144;      // Wf
  const long S5 = S4 + 262144;      // Wfef
  const long S6 = S5 + 32768;       // eh
  const long S7 = S6 + 524288;      // Wln
  const long S8 = S7 + 524288;      // Wlf  (= 11550720)
  const long S9 = S8 + 1536;        // bias iou (fp32 out)
  const long SA = S9 + 512;         // bias f
  if (g >= SA) return;
  if (g >= S9){
    long o = g - S9;
    for (int q = 0; q < 8; q++) bf_f[o+q] = ldf(bfv, o+q, f32);
    return;
  }
  if (g >= S8){
    long o = g - S8;
    for (int q = 0; q < 8; q++) biou_f[o+q] = ldf(biou, o+q, f32);
    return;
  }
  const void* src; _Float16* dst; long off;
  if      (g < S1){ src=feat;   dst=feat_h;   off=g; }
  else if (g < S2){ src=Wiou;   dst=Wiou_h;   off=g-S1; }
  else if (g < S3){ src=Wfeiou; dst=Wfeiou_h; off=g-S2; }
  else if (g < S4){ src=Wf;     dst=Wf_h;     off=g-S3; }
  else if (g < S5){ src=Wfef;   dst=Wfef_h;   off=g-S4; }
  else if (g < S6){ src=eh;     dst=eh_h;     off=g-S5; }
  else if (g < S7){ src=Wln;    dst=Wln_h;    off=g-S6; }
  else            { src=Wlf;    dst=Wlf_h;    off=g-S7; }
  #pragma unroll
  for (int q = 0; q < 8; q++) dst[off+q] = (_Float16)ldf(src, off+q, f32);
}

// ---------------- e_node/e_forw via MFMA ----------------
__global__ __launch_bounds__(64) void e_mfma(
    const _Float16* __restrict__ eh,
    const _Float16* __restrict__ Wn,
    const _Float16* __restrict__ Wf,
    float* __restrict__ e_node, float* __restrict__ e_forw)
{
  int lane = threadIdx.x;
  int m = lane & 15, quad = lane >> 4;
  int n = blockIdx.x*16 + m;
  const _Float16* wrow = (n < 512) ? (Wn + (long)n*1024) : (Wf + (long)(n-512)*1024);
  f32x4 acc[2] = {};
  for (int ks = 0; ks < 32; ks++){
    int kk = ks*32 + quad*8;
    half8 bfr = *(const half8*)(wrow + kk);
    #pragma unroll
    for (int i = 0; i < 2; i++){
      half8 afr = *(const half8*)(eh + (long)(i*16 + m)*1024 + kk);
      acc[i] = __builtin_amdgcn_mfma_f32_16x16x32_f16(afr, bfr, acc[i], 0, 0, 0);
    }
  }
  float* dst = (n < 512) ? e_node : e_forw;
  int col = (n < 512) ? n : (n - 512);
  #pragma unroll
  for (int i = 0; i < 2; i++)
    #pragma unroll
    for (int reg = 0; reg < 4; reg++){
      int b = i*16 + quad*4 + reg;
      dst[b*FEAT + col] = acc[i][reg];
    }
}

// ---------------- feat2: 4 nodes per 256-thr block (wave per node) -------------
__global__ __launch_bounds__(256) void feat2_kernel(
    const _Float16* __restrict__ feat,
    const int* __restrict__ finlist,
    const float* __restrict__ e_node,
    _Float16* __restrict__ feat2){
  int b = blockIdx.y;
  int wavei = threadIdx.x >> 6, lane = threadIdx.x & 63;
  int i = blockIdx.x*4 + wavei;
  if (i >= NN) return;
  int s0 = finlist[(b*NN+i)*2+0];
  int e0 = finlist[(b*NN+i)*2+1];
  s0 = min(max(s0, 0), NN-1);
  e0 = min(max(e0, s0), NN-1);
  int w = min(e0 - s0 + 1, 4);

  const _Float16* base = feat + ((long)b*NN + s0)*FEAT + lane*8;
  half8 v[4];
  #pragma unroll
  for (int q = 0; q < 4; q++){
    if (q < w) v[q] = *(const half8*)(base + (long)q*FEAT);
    else       v[q] = half8{};
  }
  const float* ep = e_node + b*FEAT + lane*8;
  f32x4 ev0 = *(const f32x4*)ep;
  f32x4 ev1 = *(const f32x4*)(ep+4);
  float en[8] = {ev0[0],ev0[1],ev0[2],ev0[3],ev1[0],ev1[1],ev1[2],ev1[3]};

  float s[4];
  #pragma unroll
  for (int q = 0; q < 4; q++){
    float acc = 0.f;
    #pragma unroll
    for (int j = 0; j < 8; j++) acc += (float)v[q][j]*en[j];
    s[q] = acc;
  }
  #pragma unroll
  for (int q = 0; q < 4; q++)
    #pragma unroll
    for (int off = 1; off < 64; off <<= 1)
      s[q] += __shfl_xor(s[q], off, 64);

  float mx = -1e30f;
  #pragma unroll
  for (int q = 0; q < 4; q++){
    if (q >= w) s[q] = -1e30f;
    mx = fmaxf(mx, s[q]);
  }
  float p[4]; float den = 0.f;
  #pragma unroll
  for (int q = 0; q < 4; q++){ p[q] = (q < w) ? expf(s[q]-mx) : 0.f; den += p[q]; }
  float inv = 1.f/den;

  half8 o;
  #pragma unroll
  for (int j = 0; j < 8; j++){
    float acc = 0.f;
    #pragma unroll
    for (int q = 0; q < 4; q++) acc += p[q]*(float)v[q][j];
    o[j] = (_Float16)(acc*inv);
  }
  *(half8*)(feat2 + ((long)b*NN + i)*FEAT + lane*8) = o;
}

// ---------------- fe GEMM: 128x128 tile (m97 shape), LDS-staged, dbuf ----------
// dcg<12: iou cols [dcg*128..); dcg 12..15: f cols [(dcg-12)*128..)
__global__ __launch_bounds__(256) void fe_gemm(
    const _Float16* __restrict__ feat2,
    const _Float16* __restrict__ Wfeiou, const _Float16* __restrict__ Wfef,
    const float* __restrict__ biou, const float* __restrict__ bf,
    _Float16* __restrict__ fe_iou, _Float16* __restrict__ fe_f)
{
  __shared__ _Float16 Abuf[2][128*64];
  __shared__ _Float16 Bbuf[2][128*64];
  const int MT = 32*NN;                // 16352
  int tid = threadIdx.x;
  int wv = tid >> 6, lane = tid & 63;
  int m = lane & 15, quad = lane >> 4;
  int dcg = blockIdx.y;
  int rowbase = blockIdx.x*128;
  int which = (dcg < 12) ? 0 : 1;
  int colbase = which ? (dcg-12)*128 : dcg*128;
  const _Float16* W = which ? Wfef : Wfeiou;

  const _Float16* gA[4];
  #pragma unroll
  for (int t = 0; t < 4; t++){
    int c = wv*64 + lane + t*256;
    int rt = c >> 3, kc = c & 7;
    int r = rowbase + rt; if (r >= MT) r = MT - 1;
    int bb = r / NN, node = r - bb*NN;
    int srcn = which ? ((node >= 1) ? ((node-1)>>1) : 0) : node;
    gA[t] = feat2 + ((long)bb*NN + srcn)*FEAT + ((kc ^ (rt & 7))<<3);
  }
  const _Float16* gB[4];
  #pragma unroll
  for (int t = 0; t < 4; t++){
    int c = wv*64 + lane + t*256;
    int rt = c >> 3, kc = c & 7;
    gB[t] = W + (long)(colbase + rt)*FEAT + ((kc ^ (rt & 7))<<3);
  }

  int aoff[2][2], boff[8][2];
  #pragma unroll
  for (int i = 0; i < 2; i++)
    #pragma unroll
    for (int ks = 0; ks < 2; ks++){
      int rt = wv*32 + i*16 + m;
      aoff[i][ks] = rt*128 + (((ks*4 + quad) ^ (rt & 7))<<4);
    }
  #pragma unroll
  for (int j = 0; j < 8; j++)
    #pragma unroll
    for (int ks = 0; ks < 2; ks++){
      int rt = j*16 + m;
      boff[j][ks] = rt*128 + (((ks*4 + quad) ^ (rt & 7))<<4);
    }

  f32x4 acc[2][8] = {};

  #pragma unroll
  for (int t = 0; t < 4; t++){
    gload_lds16(gA[t], &Abuf[0][(wv*64 + t*256)*8]);
    gload_lds16(gB[t], &Bbuf[0][(wv*64 + t*256)*8]);
  }

  for (int it = 0; it < 8; ++it){
    int cur = it & 1;
    __syncthreads();
    if (it < 7){
      int kk = (it+1)*64;
      #pragma unroll
      for (int t = 0; t < 4; t++){
        gload_lds16(gA[t] + kk, &Abuf[cur^1][(wv*64 + t*256)*8]);
        gload_lds16(gB[t] + kk, &Bbuf[cur^1][(wv*64 + t*256)*8]);
      }
    }
    const char* Ab_ = (const char*)&Abuf[cur][0];
    const char* Bb_ = (const char*)&Bbuf[cur][0];
    #pragma unroll
    for (int ks = 0; ks < 2; ks++){
      half8 a0 = *(const half8*)(Ab_ + aoff[0][ks]);
      half8 a1 = *(const half8*)(Ab_ + aoff[1][ks]);
      #pragma unroll
      for (int j = 0; j < 8; j++){
        half8 bfr = *(const half8*)(Bb_ + boff[j][ks]);
        acc[0][j] = __builtin_amdgcn_mfma_f32_16x16x32_f16(a0, bfr, acc[0][j], 0, 0, 0);
        acc[1][j] = __builtin_amdgcn_mfma_f32_16x16x32_f16(a1, bfr, acc[1][j], 0, 0, 0);
      }
    }
  }
  __syncthreads();

  const float* bias = which ? bf : biou;
  float bs[8];
  #pragma unroll
  for (int j = 0; j < 8; j++) bs[j] = bias[colbase + j*16 + m];

  _Float16* sl = &Abuf[0][wv*16*72];
  int lr = lane >> 2;
  int lc = (lane & 3) * 16;
  #pragma unroll
  for (int i = 0; i < 2; i++){
    #pragma unroll
    for (int jh = 0; jh < 2; jh++){
      #pragma unroll
      for (int j2 = 0; j2 < 4; j2++)
        #pragma unroll
        for (int reg = 0; reg < 4; reg++)
          sl[(quad*4+reg)*72 + j2*16 + m] = (_Float16)(acc[i][jh*4+j2][reg] + bs[jh*4+j2]);
      half8 o0 = *(const half8*)&sl[lr*72 + lc];
      half8 o1 = *(const half8*)&sl[lr*72 + lc + 8];
      int r = rowbase + wv*32 + i*16 + lr;
      if (r < MT){
        int b = r / NN, node = r - b*NN;
        if (which == 0){
          _Float16* dst = fe_iou + ((long)b*NN + node)*1536 + colbase + jh*64 + lc;
          *(half8*)dst = o0; *(half8*)(dst+8) = o1;
        } else if (node >= 1){
          _Float16* dst = fe_f + ((long)b*NN + node)*FEAT + colbase + jh*64 + lc;
          *(half8*)dst = o0; *(half8*)(dst+8) = o1;
        }
      }
    }
  }
}

// ---------------- staged per-level GEMM (P>=32), 128x128 tile ---------
// dcg<12: iou (hsum A); 12..15: f_left; 16..19: f_right
__global__ __launch_bounds__(256) void gemm_level_staged(
    int P, int lp,
    const _Float16* __restrict__ hbuf, const _Float16* __restrict__ hsum,
    const _Float16* __restrict__ Wiou, const _Float16* __restrict__ Wf,
    _Float16* __restrict__ fe_iou, _Float16* __restrict__ fe_f)
{
  __shared__ _Float16 Abuf[2][128*64];
  __shared__ _Float16 Bbuf[2][128*64];
  int Mtot = P << 5;
  int tid = threadIdx.x;
  int wv = tid >> 6, lane = tid & 63;
  int m = lane & 15, quad = lane >> 4;
  int dcg = blockIdx.y;
  int rowbase = blockIdx.x*128;
  int p0 = P - 1, c0 = 2*P - 1;
  int which, colbase;
  if (dcg < 12)      { which = 0; colbase = dcg*128; }
  else if (dcg < 16) { which = 1; colbase = (dcg-12)*128; }
  else               { which = 2; colbase = (dcg-16)*128; }
  const _Float16* W = (which == 0) ? Wiou : Wf;

  const _Float16* gA[4];
  #pragma unroll
  for (int t = 0; t < 4; t++){
    int c = wv*64 + lane + t*256;
    int rt = c >> 3, kc = c & 7;
    int r = rowbase + rt; if (r >= Mtot) r = Mtot - 1;
    int bb = r >> lp, p = r & (P-1);
    const _Float16* base;
    if (which == 0) base = hsum + ((long)bb*128 + p)*FEAT;
    else            base = hbuf + ((long)bb*NN + c0 + 2*p + (which==2))*FEAT;
    gA[t] = base + ((kc ^ (rt & 7))<<3);
  }
  const _Float16* gB[4];
  #pragma unroll
  for (int t = 0; t < 4; t++){
    int c = wv*64 + lane + t*256;
    int rt = c >> 3, kc = c & 7;
    gB[t] = W + (long)(colbase + rt)*FEAT + ((kc ^ (rt & 7))<<3);
  }

  int aoff[2][2], boff[8][2];
  #pragma unroll
  for (int i = 0; i < 2; i++)
    #pragma unroll
    for (int ks = 0; ks < 2; ks++){
      int rt = wv*32 + i*16 + m;
      aoff[i][ks] = rt*128 + (((ks*4 + quad) ^ (rt & 7))<<4);
    }
  #pragma unroll
  for (int j = 0; j < 8; j++)
    #pragma unroll
    for (int ks = 0; ks < 2; ks++){
      int rt = j*16 + m;
      boff[j][ks] = rt*128 + (((ks*4 + quad) ^ (rt & 7))<<4);
    }

  f32x4 acc[2][8] = {};

  #pragma unroll
  for (int t = 0; t < 4; t++){
    gload_lds16(gA[t], &Abuf[0][(wv*64 + t*256)*8]);
    gload_lds16(gB[t], &Bbuf[0][(wv*64 + t*256)*8]);
  }

  for (int it = 0; it < 8; ++it){
    int cur = it & 1;
    __syncthreads();
    if (it < 7){
      int kk = (it+1)*64;
      #pragma unroll
      for (int t = 0; t < 4; t++){
        gload_lds16(gA[t] + kk, &Abuf[cur^1][(wv*64 + t*256)*8]);
        gload_lds16(gB[t] + kk, &Bbuf[cur^1][(wv*64 + t*256)*8]);
      }
    }
    const char* Ab_ = (const char*)&Abuf[cur][0];
    const char* Bb_ = (const char*)&Bbuf[cur][0];
    #pragma unroll
    for (int ks = 0; ks < 2; ks++){
      half8 a0 = *(const half8*)(Ab_ + aoff[0][ks]);
      half8 a1 = *(const half8*)(Ab_ + aoff[1][ks]);
      #pragma unroll
      for (int j = 0; j < 8; j++){
        half8 bfr = *(const half8*)(Bb_ + boff[j][ks]);
        acc[0][j] = __builtin_amdgcn_mfma_f32_16x16x32_f16(a0, bfr, acc[0][j], 0, 0, 0);
        acc[1][j] = __builtin_amdgcn_mfma_f32_16x16x32_f16(a1, bfr, acc[1][j], 0, 0, 0);
      }
    }
  }
  __syncthreads();

  // f32 repack (single rounding on fe add) + vectorized RMW; wave-private slice.
  float* fsl = (float*)((char*)&Abuf[0][0] + wv*(16*68*4));
  int lr = lane >> 2;
  int lc = (lane & 3) * 16;
  #pragma unroll
  for (int i = 0; i < 2; i++){
    #pragma unroll
    for (int jh = 0; jh < 2; jh++){
      #pragma unroll
      for (int j2 = 0; j2 < 4; j2++)
        #pragma unroll
        for (int reg = 0; reg < 4; reg++)
          fsl[(quad*4+reg)*68 + j2*16 + m] = acc[i][jh*4+j2][reg];
      f32x4 a0 = *(const f32x4*)&fsl[lr*68 + lc];
      f32x4 a1 = *(const f32x4*)&fsl[lr*68 + lc + 4];
      f32x4 a2 = *(const f32x4*)&fsl[lr*68 + lc + 8];
      f32x4 a3 = *(const f32x4*)&fsl[lr*68 + lc + 12];
      int r = rowbase + wv*32 + i*16 + lr;
      if (r < Mtot){
        int b = r >> lp, p = r & (P-1);
        _Float16* dst;
        if (which == 0) dst = fe_iou + ((long)b*NN + p0 + p)*1536 + colbase + jh*64 + lc;
        else            dst = fe_f  + ((long)b*NN + c0 + 2*p + (which-1))*FEAT + colbase + jh*64 + lc;
        half8 f0 = *(const half8*)dst;
        half8 f1 = *(const half8*)(dst+8);
        half8 o0, o1;
        #pragma unroll
        for (int q = 0; q < 4; q++){
          o0[q]   = (_Float16)(a0[q] + (float)f0[q]);
          o0[q+4] = (_Float16)(a1[q] + (float)f0[q+4]);
          o1[q]   = (_Float16)(a2[q] + (float)f1[q]);
          o1[q+4] = (_Float16)(a3[q] + (float)f1[q+4]);
        }
        *(half8*)dst = o0; *(half8*)(dst+8) = o1;
      }
    }
  }
}

// ---------------- per-level GEMM, one-wave form (P<=16, verified) ----------
__global__ __launch_bounds__(64) void gemm_level_h(
    int P, int lp,
    const _Float16* __restrict__ hbuf,
    const _Float16* __restrict__ Wiou, const _Float16* __restrict__ Wf,
    _Float16* __restrict__ fe_iou, _Float16* __restrict__ fe_f)
{
  __shared__ float ldsf[16*64];
  int lane = threadIdx.x;
  int m = lane & 15, quad = lane >> 4;
  int cg = blockIdx.y;
  int Mtot = P << 5;
  int rowbase = blockIdx.x*64;
  if (rowbase >= Mtot) return;
  int p0 = P - 1, c0 = 2*P - 1;

  int which, colbase;
  if (cg < 24)      { which = 0; colbase = cg*64; }
  else if (cg < 32) { which = 1; colbase = (cg-24)*64; }
  else              { which = 2; colbase = (cg-32)*64; }

  const _Float16* W = (which == 0) ? Wiou : Wf;
  bool dual = (which == 0);

  f32x4 acc[4][4] = {};
  const _Float16* ap[4];
  const _Float16* wp[4];
  #pragma unroll
  for (int i = 0; i < 4; i++){
    int r = rowbase + i*16 + m;
    if (r >= Mtot) r = Mtot - 1;
    int b = r >> lp, p = r & (P-1);
    int node = c0 + 2*p + ((which == 2) ? 1 : 0);
    ap[i] = hbuf + ((long)b*NN + node)*FEAT + quad*8;
    wp[i] = W + (long)(colbase + i*16 + m)*FEAT + quad*8;
  }

  half8 Ab[3][4], A2b[3][4], Bb[3][4];
  #pragma unroll
  for (int s = 0; s < 2; s++){
    long kk = (long)s*32;
    #pragma unroll
    for (int i = 0; i < 4; i++){
      Ab[s][i] = *(const half8*)(ap[i] + kk);
      if (dual) A2b[s][i] = *(const half8*)(ap[i] + FEAT + kk);
      Bb[s][i] = *(const half8*)(wp[i] + kk);
    }
  }
  #pragma unroll
  for (int ks = 0; ks < 16; ++ks){
    int cur = ks % 3;
    if (ks + 2 < 16){
      int nxt = (ks + 2) % 3;
      long kk = (long)(ks + 2)*32;
      #pragma unroll
      for (int i = 0; i < 4; i++){
        Ab[nxt][i] = *(const half8*)(ap[i] + kk);
        if (dual) A2b[nxt][i] = *(const half8*)(ap[i] + FEAT + kk);
        Bb[nxt][i] = *(const half8*)(wp[i] + kk);
      }
    }
    half8 av[4];
    #pragma unroll
    for (int i = 0; i < 4; i++){
      av[i] = Ab[cur][i];
      if (dual) av[i] = av[i] + A2b[cur][i];
    }
    #pragma unroll
    for (int i = 0; i < 4; i++)
      #pragma unroll
      for (int j = 0; j < 4; j++)
        acc[i][j] = __builtin_amdgcn_mfma_f32_16x16x32_f16(av[i], Bb[cur][j], acc[i][j], 0, 0, 0);
  }

  int lr = lane >> 2;
  int lc = (lane & 3) * 16;
  #pragma unroll
  for (int i = 0; i < 4; i++){
    #pragma unroll
    for (int j = 0; j < 4; j++)
      #pragma unroll
      for (int reg = 0; reg < 4; reg++)
        ldsf[(quad*4+reg)*64 + j*16 + m] = acc[i][j][reg];
    __syncthreads();
    f32x4 a0 = *(const f32x4*)&ldsf[lr*64 + lc];
    f32x4 a1 = *(const f32x4*)&ldsf[lr*64 + lc + 4];
    f32x4 a2 = *(const f32x4*)&ldsf[lr*64 + lc + 8];
    f32x4 a3 = *(const f32x4*)&ldsf[lr*64 + lc + 12];
    int r = rowbase + i*16 + lr;
    if (r < Mtot){
      int b = r >> lp, p = r & (P-1);
      _Float16* dst;
      if (which == 0) dst = fe_iou + ((long)b*NN + p0 + p)*1536 + colbase + lc;
      else            dst = fe_f  + ((long)b*NN + c0 + 2*p + (which-1))*FEAT + colbase + lc;
      half8 f0 = *(const half8*)dst;
      half8 f1 = *(const half8*)(dst+8);
      half8 o0, o1;
      #pragma unroll
      for (int q = 0; q < 4; q++){
        o0[q]   = (_Float16)(a0[q] + (float)f0[q]);
        o0[q+4] = (_Float16)(a1[q] + (float)f0[q+4]);
        o1[q]   = (_Float16)(a2[q] + (float)f1[q]);
        o1[q+4] = (_Float16)(a3[q] + (float)f1[q+4]);
      }
      *(half8*)dst = o0; *(half8*)(dst+8) = o1;
    }
    __syncthreads();
  }
}

// ---------------- level-0 pointwise (leaves), paired, + hsum (verified R10) ------
__global__ void pw_leaf(const _Float16* __restrict__ fe_iou, float* __restrict__ c,
                        _Float16* __restrict__ h, _Float16* __restrict__ hsum){
  int r2 = blockIdx.x, b = blockIdx.y, t = threadIdx.x;   // r2 < 128
  int l0 = 255 + 2*r2;
  const _Float16* row0 = fe_iou + ((long)b*NN + l0)*1536;
  const _Float16* row1 = row0 + 1536;
  long off0 = ((long)b*NN + l0)*FEAT;
  long off1 = off0 + FEAT;
  long so = ((long)b*128 + r2)*FEAT;
  #pragma unroll
  for (int e = 0; e < 2; e++){
    int f = t + e*256;
    float cn0 = sigm((float)row0[f])*fmaxf((float)row0[2*FEAT+f], 0.f);
    _Float16 hn0 = (_Float16)(sigm((float)row0[FEAT+f])*tanhf(cn0));
    float cn1 = sigm((float)row1[f])*fmaxf((float)row1[2*FEAT+f], 0.f);
    _Float16 hn1 = (_Float16)(sigm((float)row1[FEAT+f])*tanhf(cn1));
    c[off0+f] = cn0; h[off0+f] = hn0;
    c[off1+f] = cn1; h[off1+f] = hn1;
    hsum[so+f] = hn0 + hn1;
  }
}

// ---------------- level-n pointwise, paired, + hsum (verified R10) ----------------
__global__ void pw_level(const _Float16* __restrict__ fe_iou, const _Float16* __restrict__ fe_f,
                         float* __restrict__ c, _Float16* __restrict__ h,
                         _Float16* __restrict__ hsum,
                         int P, int p0, int c0){
  int r2 = blockIdx.x, b = blockIdx.y, t = threadIdx.x;
  int pr0 = 2*r2, pr1 = 2*r2 + 1;
  bool has1 = (pr1 < P);
  const _Float16* row0 = fe_iou + ((long)b*NN + p0 + pr0)*1536;
  const _Float16* fl0 = fe_f + ((long)b*NN + c0 + 2*pr0)*FEAT;
  long cl0 = ((long)b*NN + c0 + 2*pr0)*FEAT;
  long po0 = ((long)b*NN + p0 + pr0)*FEAT;
  long so = ((long)b*128 + r2)*FEAT;
  #pragma unroll
  for (int e = 0; e < 2; e++){
    int f = t + e*256;
    float cs0 = sigm((float)fl0[f])*c[cl0+f] + sigm((float)fl0[FEAT+f])*c[cl0+FEAT+f];
    float cn0 = sigm((float)row0[f])*fmaxf((float)row0[2*FEAT+f], 0.f) + cs0;
    _Float16 hn0 = (_Float16)(sigm((float)row0[FEAT+f])*tanhf(cn0));
    c[po0+f] = cn0; h[po0+f] = hn0;
    if (has1){
      const _Float16* row1 = row0 + 1536;
      const _Float16* fl1 = fl0 + 2*FEAT;
      long cl1 = cl0 + 2*FEAT;
      float cs1 = sigm((float)fl1[f])*c[cl1+f] + sigm((float)fl1[FEAT+f])*c[cl1+FEAT+f];
      float cn1 = sigm((float)row1[f])*fmaxf((float)row1[2*FEAT+f], 0.f) + cs1;
      _Float16 hn1 = (_Float16)(sigm((float)row1[FEAT+f])*tanhf(cn1));
      c[po0+FEAT+f] = cn1; h[po0+FEAT+f] = hn1;
      hsum[so+f] = hn0 + hn1;
    }
  }
}

// ---------------- logits[b,i] = dot(h[b,i,:], e_forw[b,:]) ----------------
__global__ void logits_kernel(const _Float16* __restrict__ h,
                              const float* __restrict__ e_forw,
                              float* __restrict__ logits){
  int b = blockIdx.y;
  int wave = threadIdx.x >> 6, lane = threadIdx.x & 63;
  int i = blockIdx.x*4 + wave;
  if (i >= NN) return;
  half8 hv = *(const half8*)(h + ((long)b*NN+i)*FEAT + lane*8);
  const float* ef = e_forw + b*FEAT + lane*8;
  float s = 0.f;
  #pragma unroll
  for (int q = 0; q < 8; q++) s += (float)hv[q]*ef[q];
  #pragma unroll
  for (int off = 32; off > 0; off >>= 1) s += __shfl_down(s, off, 64);
  if (lane == 0) logits[b*NN+i] = s;
}

// ---------------- softmax + weighted sum (verified R13) ----------
__global__ __launch_bounds__(64) void out_kernel(
    const _Float16* __restrict__ h,
    const float* __restrict__ logits,
    float* __restrict__ out){
  __shared__ float sprob[NN+1];
  int b = blockIdx.x, yc = blockIdx.y, lane = threadIdx.x;
  float mx = -1e30f;
  for (int i = lane; i < NN; i += 64) mx = fmaxf(mx, logits[b*NN+i]);
  #pragma unroll
  for (int off = 32; off > 0; off >>= 1) mx = fmaxf(mx, __shfl_xor(mx, off, 64));
  float sum = 0.f;
  for (int i = lane; i < NN; i += 64){
    float p = expf(logits[b*NN+i]-mx);
    sprob[i] = p; sum += p;
  }
  #pragma unroll
  for (int off = 32; off > 0; off >>= 1) sum += __shfl_xor(sum, off, 64);
  float inv = 1.f/sum;
  __syncthreads();

  int sub = lane >> 3;
  int fl  = (lane & 7) * 8;
  const _Float16* hp = h + (long)b*NN*FEAT + yc*64 + fl;
  float acc[8] = {};
  for (int i = sub; i < NN; i += 8){
    float p = sprob[i];
    half8 hv = *(const half8*)(hp + (long)i*FEAT);
    #pragma unroll
    for (int q = 0; q < 8; q++) acc[q] += p*(float)hv[q];
  }
  #pragma unroll
  for (int q = 0; q < 8; q++){
    #pragma unroll
    for (int off = 8; off < 64; off <<= 1)
      acc[q] += __shfl_xor(acc[q], off, 64);
  }
  if (sub == 0){
    float* dst = out + b*FEAT + yc*64 + fl;
    #pragma unroll
    for (int q = 0; q < 8; q++) dst[q] = acc[q]*inv;
  }
}

extern "C" void kernel_launch(void* const* d_in, const int* in_sizes, int n_in,
                              void* d_out, int out_size, void* d_ws, size_t ws_size,
                              hipStream_t stream){
  (void)in_sizes; (void)n_in; (void)out_size; (void)ws_size;
  const void* feat_raw   = d_in[0];
  const int*  finlist    = (const int*)d_in[4];
  const void* eh_raw     = d_in[5];
  const void* Wln_raw    = d_in[6];
  const void* Wlf_raw    = d_in[7];
  const void* Wiou_raw   = d_in[8];
  const void* Wfeiou_raw = d_in[9];
  const void* bfeiou_raw = d_in[10];
  const void* Wf_raw     = d_in[11];
  const void* Wfef_raw   = d_in[12];
  const void* bfef_raw   = d_in[13];

  char* ws = (char*)d_ws;
  size_t off = 0;
  auto alloc = [&](size_t bytes)->char*{
    char* p = ws + off; off += (bytes + 255) & ~(size_t)255; return p;
  };
  int*      flag     = (int*)alloc(256);
  _Float16* feat_h   = (_Float16*)alloc((size_t)NFEAT*2);   // reused as fe_f after feat2_kernel
  _Float16* Wiou_h   = (_Float16*)alloc((size_t)1536*512*2);
  _Float16* Wfeiou_h = (_Float16*)alloc((size_t)1536*512*2);
  _Float16* Wf_h     = (_Float16*)alloc((size_t)512*512*2);
  _Float16* Wfef_h   = (_Float16*)alloc((size_t)512*512*2);
  _Float16* eh_h     = (_Float16*)alloc((size_t)32*1024*2);
  _Float16* Wln_h    = (_Float16*)alloc((size_t)512*1024*2);
  _Float16* Wlf_h    = (_Float16*)alloc((size_t)512*1024*2);
  float*    bfeiou_f = (float*)alloc((size_t)1536*4);
  float*    bfef_f   = (float*)alloc((size_t)512*4);
  float*    e_node   = (float*)alloc((size_t)32*512*4);
  float*    e_forw   = (float*)alloc((size_t)32*512*4);
  _Float16* feat2    = (_Float16*)alloc((size_t)NFEAT*2);
  _Float16* h_half   = (_Float16*)alloc((size_t)NFEAT*2);
  float*    c_buf    = (float*)alloc((size_t)NFEAT*4);
  _Float16* fe_iou   = (_Float16*)alloc((size_t)32*NN*1536*2);  // 50.2 MB
  _Float16* hsum     = (_Float16*)alloc((size_t)32*128*512*2);  // 4 MB
  float*    logits   = (float*)alloc((size_t)32*NN*4);
  _Float16* fe_f     = feat_h;   // overlay: feat_h dead after feat2_kernel

  detect_kernel<<<dim3(1), 256, 0, stream>>>((const unsigned short*)feat_raw, flag);

  cvt_all<<<dim3(5641), 256, 0, stream>>>(
      feat_raw, Wiou_raw, Wfeiou_raw, Wf_raw, Wfef_raw, eh_raw, Wln_raw, Wlf_raw,
      bfeiou_raw, bfef_raw,
      feat_h, Wiou_h, Wfeiou_h, Wf_h, Wfef_h, eh_h, Wln_h, Wlf_h,
      bfeiou_f, bfef_f, flag);

  e_mfma<<<dim3(64), 64, 0, stream>>>(eh_h, Wln_h, Wlf_h, e_node, e_forw);
  feat2_kernel<<<dim3(128,32), 256, 0, stream>>>(feat_h, finlist, e_node, feat2);

  // fe GEMM: 128x128 tiles; grid x = rowtiles (fast), y = 12 iou + 4 f = 16.
  fe_gemm<<<dim3(128, 16), 256, 0, stream>>>(
      feat2, Wfeiou_h, Wfef_h, bfeiou_f, bfef_f, fe_iou, fe_f);

  pw_leaf<<<dim3(128,32), 256, 0, stream>>>(fe_iou, c_buf, h_half, hsum);

  for (int n = 1; n <= 8; n++){
    int P = 1 << (8-n);
    int lp = 8 - n;
    int p0 = P - 1, c0 = 2*P - 1;
    if (P >= 32){
      int rt = (32*P + 127)/128;
      gemm_level_staged<<<dim3(rt, 20), 256, 0, stream>>>(P, lp,
          h_half, hsum, Wiou_h, Wf_h, fe_iou, fe_f);
    } else {
      int gy = (32*P + 63)/64;
      gemm_level_h<<<dim3(gy, 40), 64, 0, stream>>>(P, lp,
          h_half, Wiou_h, Wf_h, fe_iou, fe_f);
    }
    pw_level<<<dim3((P+1)/2,32), 256, 0, stream>>>(fe_iou, fe_f, c_buf, h_half, hsum, P, p0, c0);
  }

  logits_kernel<<<dim3(128,32), 256, 0, stream>>>(h_half, e_forw, logits);
  out_kernel<<<dim3(32,8), 64, 0, stream>>>(h_half, logits, (float*)d_out);
}